// Round 1
// baseline (6586.403 us; speedup 1.0000x reference)
//
#include <hip/hip_runtime.h>
#include <math.h>

#define NB 2
#define NS 1024
#define NH 8
#define NDK 64
#define ND 512
#define NDFF 2048
#define NV 32000
#define NL 6

// ---------------------------------------------------------------- embed
__global__ void embed_kernel(const int* __restrict__ tokens,
                             const float* __restrict__ emb,
                             float* __restrict__ x) {
  const int row = blockIdx.x;            // b*NS + s
  const int s = row & (NS - 1);
  const int tok = tokens[row];
  const int tid = threadIdx.x;
  const float SQRTD = 22.627416997969522f;             // sqrt(512)
  const float C = -9.210340371976184f / (float)ND;     // -ln(10000)/D
#pragma unroll
  for (int i = 0; i < 2; ++i) {
    const int d = tid + i * 256;
    const int pair = d >> 1;
    const float div = expf((float)(2 * pair) * C);
    const float ang = (float)s * div;
    const float pe = (d & 1) ? cosf(ang) : sinf(ang);
    x[(size_t)row * ND + d] = emb[(size_t)tok * ND + d] * SQRTD + pe;
  }
}

// ---------------------------------------------------------------- GEMM
// C[M,N] = A[M,K] @ W[K,N] + bias ; ACT 0=none 1=gelu(exact)
// M,N,K all divisible by tile dims for every call site here.
template <int ACT>
__global__ __launch_bounds__(256)
void gemm_bias_kernel(const float* __restrict__ A, const float* __restrict__ W,
                      const float* __restrict__ bias, float* __restrict__ C,
                      int M, int N, int K) {
  __shared__ float As[16][65];   // [kk][m], +1 pad
  __shared__ float Bs[16][64];   // [kk][n]
  const int tid = threadIdx.x;
  const int tx = tid & 15, ty = tid >> 4;
  const int m0 = blockIdx.y * 64, n0 = blockIdx.x * 64;
  float c[4][4] = {};
  for (int k0 = 0; k0 < K; k0 += 16) {
#pragma unroll
    for (int i = 0; i < 4; ++i) {
      const int idx = tid + i * 256;
      const int m = idx >> 4, kk = idx & 15;
      As[kk][m] = A[(size_t)(m0 + m) * K + k0 + kk];
      const int kb = idx >> 6, n = idx & 63;
      Bs[kb][n] = W[(size_t)(k0 + kb) * N + n0 + n];
    }
    __syncthreads();
#pragma unroll
    for (int kk = 0; kk < 16; ++kk) {
      float a[4], bv[4];
#pragma unroll
      for (int i = 0; i < 4; ++i) a[i] = As[kk][ty * 4 + i];
#pragma unroll
      for (int j = 0; j < 4; ++j) bv[j] = Bs[kk][tx * 4 + j];
#pragma unroll
      for (int i = 0; i < 4; ++i)
#pragma unroll
        for (int j = 0; j < 4; ++j) c[i][j] += a[i] * bv[j];
    }
    __syncthreads();
  }
#pragma unroll
  for (int i = 0; i < 4; ++i) {
    const int row = m0 + ty * 4 + i;
#pragma unroll
    for (int j = 0; j < 4; ++j) {
      const int col = n0 + tx * 4 + j;
      float v = c[i][j] + bias[col];
      if (ACT == 1) v = 0.5f * v * (1.0f + erff(v * 0.7071067811865476f));
      C[(size_t)row * N + col] = v;
    }
  }
}

// ---------------------------------------------------------------- attention scores+softmax
// grid (s, h, b); block 256. probs points at this layer's [B,H,S,S] slice of d_out.
__global__ __launch_bounds__(256)
void attn_kernel(const float* __restrict__ q, const float* __restrict__ k,
                 float* __restrict__ probs) {
  const int s = blockIdx.x, h = blockIdx.y, b = blockIdx.z;
  const int tid = threadIdx.x;
  __shared__ float qs[NDK];
  __shared__ float red[256];
  if (tid < NDK) qs[tid] = q[((size_t)(b * NS + s) * NH + h) * NDK + tid];
  __syncthreads();

  float vals[4];
  float lmax = -1e30f;
#pragma unroll
  for (int i = 0; i < 4; ++i) {
    const int t = tid + i * 256;
    float dot = -1e30f;
    if (t <= s) {
      const float4* kp = (const float4*)(k + ((size_t)(b * NS + t) * NH + h) * NDK);
      float acc = 0.f;
#pragma unroll
      for (int d4 = 0; d4 < 16; ++d4) {
        const float4 kv = kp[d4];
        acc += qs[4 * d4] * kv.x + qs[4 * d4 + 1] * kv.y +
               qs[4 * d4 + 2] * kv.z + qs[4 * d4 + 3] * kv.w;
      }
      dot = acc * 0.125f;                 // / sqrt(64)
      lmax = fmaxf(lmax, dot);
    }
    vals[i] = dot;
  }
  red[tid] = lmax; __syncthreads();
  for (int o = 128; o > 0; o >>= 1) {
    if (tid < o) red[tid] = fmaxf(red[tid], red[tid + o]);
    __syncthreads();
  }
  const float m = red[0];
  __syncthreads();

  float lsum = 0.f;
#pragma unroll
  for (int i = 0; i < 4; ++i) {
    const int t = tid + i * 256;
    const float e = (t <= s) ? expf(vals[i] - m) : 0.f;
    vals[i] = e; lsum += e;
  }
  red[tid] = lsum; __syncthreads();
  for (int o = 128; o > 0; o >>= 1) {
    if (tid < o) red[tid] += red[tid + o];
    __syncthreads();
  }
  const float inv = 1.f / red[0];

  float* prow = probs + (((size_t)b * NH + h) * NS + s) * NS;
#pragma unroll
  for (int i = 0; i < 4; ++i) {
    const int t = tid + i * 256;
    prow[t] = vals[i] * inv;              // exact 0 above the diagonal
  }
}

// ---------------------------------------------------------------- ctx = probs @ V
// grid (s, h, b); block 64 (one lane per d)
__global__ __launch_bounds__(64)
void ctx_kernel(const float* __restrict__ probs, const float* __restrict__ v,
                float* __restrict__ ctx) {
  const int s = blockIdx.x, h = blockIdx.y, b = blockIdx.z;
  const int d = threadIdx.x;
  __shared__ float as[256];
  const float* prow = probs + (((size_t)b * NH + h) * NS + s) * NS;
  float acc = 0.f;
  for (int t0 = 0; t0 <= s; t0 += 256) {
    const int chunk = min(256, s + 1 - t0);
    for (int i = d; i < 256; i += 64)
      as[i] = (t0 + i <= s) ? prow[t0 + i] : 0.f;
    __syncthreads();
    for (int tt = 0; tt < chunk; ++tt)
      acc += as[tt] * v[((size_t)(b * NS + t0 + tt) * NH + h) * NDK + d];
    __syncthreads();
  }
  ctx[((size_t)(b * NS + s) * NH + h) * NDK + d] = acc;
}

// ---------------------------------------------------------------- residual add + LayerNorm (in place on x)
// y may be nullptr (plain LN). grid = 2048 rows, block 256.
__global__ __launch_bounds__(256)
void add_ln_kernel(float* __restrict__ x, const float* __restrict__ y,
                   const float* __restrict__ g, const float* __restrict__ bb) {
  const int row = blockIdx.x, tid = threadIdx.x;
  const size_t base = (size_t)row * ND;
  float v0 = x[base + tid], v1 = x[base + tid + 256];
  if (y) { v0 += y[base + tid]; v1 += y[base + tid + 256]; }
  __shared__ float red[256];
  red[tid] = v0 + v1; __syncthreads();
  for (int o = 128; o > 0; o >>= 1) {
    if (tid < o) red[tid] += red[tid + o];
    __syncthreads();
  }
  const float mean = red[0] * (1.f / (float)ND);
  __syncthreads();
  const float d0 = v0 - mean, d1 = v1 - mean;
  red[tid] = d0 * d0 + d1 * d1; __syncthreads();
  for (int o = 128; o > 0; o >>= 1) {
    if (tid < o) red[tid] += red[tid + o];
    __syncthreads();
  }
  const float inv = 1.f / sqrtf(red[0] * (1.f / (float)ND) + 1e-5f);
  x[base + tid]       = d0 * inv * g[tid]       + bb[tid];
  x[base + tid + 256] = d1 * inv * g[tid + 256] + bb[tid + 256];
}

// ---------------------------------------------------------------- launch
extern "C" void kernel_launch(void* const* d_in, const int* in_sizes, int n_in,
                              void* d_out, int out_size, void* d_ws, size_t ws_size,
                              hipStream_t stream) {
  const int*   tokens  = (const int*)d_in[0];
  const float* tok_emb = (const float*)d_in[1];
  const float* Wq = (const float*)d_in[2];
  const float* bq = (const float*)d_in[3];
  const float* Wk = (const float*)d_in[4];
  const float* bk = (const float*)d_in[5];
  const float* Wv = (const float*)d_in[6];
  const float* bv = (const float*)d_in[7];
  const float* Wo = (const float*)d_in[8];
  const float* bo = (const float*)d_in[9];
  const float* ln1_g = (const float*)d_in[10];
  const float* ln1_b = (const float*)d_in[11];
  const float* W1 = (const float*)d_in[12];
  const float* b1 = (const float*)d_in[13];
  const float* W2 = (const float*)d_in[14];
  const float* b2 = (const float*)d_in[15];
  const float* ln2_g = (const float*)d_in[16];
  const float* ln2_b = (const float*)d_in[17];
  const float* lnf_g = (const float*)d_in[18];
  const float* lnf_b = (const float*)d_in[19];
  const float* Wout = (const float*)d_in[20];
  const float* bout = (const float*)d_in[21];

  float* logits   = (float*)d_out;                               // [B,S,V]
  float* attn_all = (float*)d_out + (size_t)NB * NS * NV;        // [L,B,H,S,S]

  // workspace layout (floats); h overlays q..ctx after attention is done
  float* ws = (float*)d_ws;
  const size_t U = (size_t)NB * NS * ND;   // 1,048,576
  float* x   = ws;
  float* q   = ws + 1 * U;
  float* k   = ws + 2 * U;
  float* v   = ws + 3 * U;
  float* ctx = ws + 4 * U;
  float* tmp = ws + 5 * U;
  float* h   = ws + 1 * U;                  // [2048, 2048] overlays q,k,v,ctx

  const int M = NB * NS;                    // 2048 token rows

  embed_kernel<<<M, 256, 0, stream>>>(tokens, tok_emb, x);

  const dim3 gProj(ND / 64, M / 64);        // (8, 32)
  const dim3 gFF1(NDFF / 64, M / 64);       // (32, 32)
  const dim3 gAttn(NS, NH, NB);

  for (int l = 0; l < NL; ++l) {
    const float* Wq_l = Wq + (size_t)l * ND * ND;
    const float* Wk_l = Wk + (size_t)l * ND * ND;
    const float* Wv_l = Wv + (size_t)l * ND * ND;
    const float* Wo_l = Wo + (size_t)l * ND * ND;
    const float* W1_l = W1 + (size_t)l * ND * NDFF;
    const float* W2_l = W2 + (size_t)l * NDFF * ND;

    gemm_bias_kernel<0><<<gProj, 256, 0, stream>>>(x, Wq_l, bq + l * ND, q, M, ND, ND);
    gemm_bias_kernel<0><<<gProj, 256, 0, stream>>>(x, Wk_l, bk + l * ND, k, M, ND, ND);
    gemm_bias_kernel<0><<<gProj, 256, 0, stream>>>(x, Wv_l, bv + l * ND, v, M, ND, ND);

    float* probs_l = attn_all + (size_t)l * NB * NH * NS * NS;
    attn_kernel<<<gAttn, 256, 0, stream>>>(q, k, probs_l);
    ctx_kernel<<<gAttn, 64, 0, stream>>>(probs_l, v, ctx);

    gemm_bias_kernel<0><<<gProj, 256, 0, stream>>>(ctx, Wo_l, bo + l * ND, tmp, M, ND, ND);
    add_ln_kernel<<<M, 256, 0, stream>>>(x, tmp, ln1_g + l * ND, ln1_b + l * ND);

    gemm_bias_kernel<1><<<gFF1, 256, 0, stream>>>(x, W1_l, b1 + l * NDFF, h, M, NDFF, ND);
    gemm_bias_kernel<0><<<gProj, 256, 0, stream>>>(h, W2_l, b2 + l * ND, tmp, M, ND, NDFF);
    add_ln_kernel<<<M, 256, 0, stream>>>(x, tmp, ln2_g + l * ND, ln2_b + l * ND);
  }

  add_ln_kernel<<<M, 256, 0, stream>>>(x, nullptr, lnf_g, lnf_b);

  const dim3 gOut(NV / 64, M / 64);         // (500, 32)
  gemm_bias_kernel<0><<<gOut, 256, 0, stream>>>(x, Wout, bout, logits, M, NV, ND);
}

// Round 2
// 3511.764 us; speedup vs baseline: 1.8755x; 1.8755x over previous
//
#include <hip/hip_runtime.h>
#include <math.h>

#define NB 2
#define NS 1024
#define NH 8
#define NDK 64
#define ND 512
#define NDFF 2048
#define NV 32000
#define NL 6
#define MROWS (NB * NS)
#define QKVLD (3 * ND)   // 1536

using bf16_t = __bf16;
using bf16x4 = __attribute__((ext_vector_type(4))) __bf16;
using bf16x8 = __attribute__((ext_vector_type(8))) __bf16;
using f32x4  = __attribute__((ext_vector_type(4))) float;

// ---------------------------------------------------------------- embed
__global__ void embed_kernel(const int* __restrict__ tokens,
                             const float* __restrict__ emb,
                             float* __restrict__ x) {
  const int row = blockIdx.x;            // b*NS + s
  const int s = row & (NS - 1);
  const int tok = tokens[row];
  const int tid = threadIdx.x;
  const float SQRTD = 22.627416997969522f;             // sqrt(512)
  const float C = -9.210340371976184f / (float)ND;     // -ln(10000)/D
#pragma unroll
  for (int i = 0; i < 2; ++i) {
    const int d = tid + i * 256;
    const int pair = d >> 1;
    const float div = expf((float)(2 * pair) * C);
    const float ang = (float)s * div;
    const float pe = (d & 1) ? cosf(ang) : sinf(ang);
    x[(size_t)row * ND + d] = emb[(size_t)tok * ND + d] * SQRTD + pe;
  }
}

// ---------------------------------------------------------------- MFMA GEMM
// C[:, mat*N + 0..N) = A[M,K] @ Wmat[K,N] + bias_mat ; ldc = row stride of C.
// grid: (M/128, nbm * nmats). blockIdx.x = m-tile (fast → W-panel reuse in L2).
// ACT 0 = none, 1 = exact GELU.
template <int ACT>
__global__ __launch_bounds__(256)
void gemm_mfma(const float* __restrict__ A,
               const float* __restrict__ W0, const float* __restrict__ W1,
               const float* __restrict__ W2,
               const float* __restrict__ B0, const float* __restrict__ B1,
               const float* __restrict__ B2,
               float* __restrict__ C, int N, int K, int ldc, int nbm) {
  const int mat = blockIdx.y / nbm;
  const int nb  = blockIdx.y % nbm;
  const float* W    = (mat == 0) ? W0 : (mat == 1) ? W1 : W2;
  const float* bias = (mat == 0) ? B0 : (mat == 1) ? B1 : B2;
  const int m0 = blockIdx.x * 128;
  const int n0 = nb * 128;

  __shared__ bf16_t As[128 * 40];      // [m][k] rows padded 32->40
  __shared__ bf16_t Bs[4 * 128 * 8];   // [kc][n][8]

  const int tid  = threadIdx.x;
  const int lane = tid & 63;
  const int wave = tid >> 6;
  const int wm = wave >> 1, wn = wave & 1;
  const int lrow = lane & 15, kc = lane >> 4;

  const int a_kq = tid & 7, a_m = tid >> 3;     // A staging
  const int b_n = tid & 127, b_h = tid >> 7;    // B staging

  f32x4 acc[4][4] = {};

  for (int k0 = 0; k0 < K; k0 += 32) {
    // ---- stage A tile (128 x 32 f32 -> bf16)
#pragma unroll
    for (int r = 0; r < 4; ++r) {
      const int m = a_m + r * 32;
      const float4 av = *(const float4*)&A[(size_t)(m0 + m) * K + k0 + a_kq * 4];
      bf16x4 p;
      p[0] = (bf16_t)av.x; p[1] = (bf16_t)av.y;
      p[2] = (bf16_t)av.z; p[3] = (bf16_t)av.w;
      *(bf16x4*)&As[m * 40 + a_kq * 4] = p;
    }
    // ---- stage B tile (32 x 128 f32 -> bf16, transposed to [kc][n][8])
#pragma unroll
    for (int c = 0; c < 2; ++c) {
      const int kcc = b_h * 2 + c;
      bf16x8 p;
#pragma unroll
      for (int j = 0; j < 8; ++j)
        p[j] = (bf16_t)W[(size_t)(k0 + kcc * 8 + j) * N + n0 + b_n];
      *(bf16x8*)&Bs[(kcc * 128 + b_n) * 8] = p;
    }
    __syncthreads();

    bf16x8 af[4], bfv[4];
#pragma unroll
    for (int m = 0; m < 4; ++m)
      af[m] = *(const bf16x8*)&As[(wm * 64 + m * 16 + lrow) * 40 + kc * 8];
#pragma unroll
    for (int n = 0; n < 4; ++n)
      bfv[n] = *(const bf16x8*)&Bs[(kc * 128 + wn * 64 + n * 16 + lrow) * 8];
#pragma unroll
    for (int m = 0; m < 4; ++m)
#pragma unroll
      for (int n = 0; n < 4; ++n)
        acc[m][n] = __builtin_amdgcn_mfma_f32_16x16x32_bf16(af[m], bfv[n], acc[m][n], 0, 0, 0);
    __syncthreads();
  }

  const int crow0 = (lane >> 4) * 4, ccol = lane & 15;
#pragma unroll
  for (int m = 0; m < 4; ++m) {
#pragma unroll
    for (int n = 0; n < 4; ++n) {
      const int ncl = n0 + wn * 64 + n * 16 + ccol;     // col within this matrix
      const float bv = bias[ncl];
      const size_t ccol_g = (size_t)mat * N + ncl;
#pragma unroll
      for (int i = 0; i < 4; ++i) {
        const int row = m0 + wm * 64 + m * 16 + crow0 + i;
        float v = acc[m][n][i] + bv;
        if (ACT == 1) v = 0.5f * v * (1.0f + erff(v * 0.7071067811865476f));
        C[(size_t)row * ldc + ccol_g] = v;
      }
    }
  }
}

// ---------------------------------------------------------------- attention scores+softmax
// grid (s, h, b); block 256. probs -> this layer's [B,H,S,S] slice of d_out.
__global__ __launch_bounds__(256)
void attn_kernel(const float* __restrict__ qkv, float* __restrict__ probs) {
  const int s = blockIdx.x, h = blockIdx.y, b = blockIdx.z;
  const int tid = threadIdx.x;
  __shared__ float qs[NDK];
  __shared__ float red[256];
  if (tid < NDK) qs[tid] = qkv[(size_t)(b * NS + s) * QKVLD + h * NDK + tid];
  __syncthreads();

  float vals[4];
  float lmax = -1e30f;
#pragma unroll
  for (int i = 0; i < 4; ++i) {
    const int t = tid + i * 256;
    float dot = -1e30f;
    if (t <= s) {
      const float4* kp = (const float4*)(qkv + (size_t)(b * NS + t) * QKVLD + ND + h * NDK);
      float acc = 0.f;
#pragma unroll
      for (int d4 = 0; d4 < 16; ++d4) {
        const float4 kv = kp[d4];
        acc += qs[4 * d4] * kv.x + qs[4 * d4 + 1] * kv.y +
               qs[4 * d4 + 2] * kv.z + qs[4 * d4 + 3] * kv.w;
      }
      dot = acc * 0.125f;                 // / sqrt(64)
      lmax = fmaxf(lmax, dot);
    }
    vals[i] = dot;
  }
  red[tid] = lmax; __syncthreads();
  for (int o = 128; o > 0; o >>= 1) {
    if (tid < o) red[tid] = fmaxf(red[tid], red[tid + o]);
    __syncthreads();
  }
  const float m = red[0];
  __syncthreads();

  float lsum = 0.f;
#pragma unroll
  for (int i = 0; i < 4; ++i) {
    const int t = tid + i * 256;
    const float e = (t <= s) ? expf(vals[i] - m) : 0.f;
    vals[i] = e; lsum += e;
  }
  red[tid] = lsum; __syncthreads();
  for (int o = 128; o > 0; o >>= 1) {
    if (tid < o) red[tid] += red[tid + o];
    __syncthreads();
  }
  const float inv = 1.f / red[0];

  float* prow = probs + (((size_t)b * NH + h) * NS + s) * NS;
#pragma unroll
  for (int i = 0; i < 4; ++i) {
    const int t = tid + i * 256;
    prow[t] = vals[i] * inv;              // exact 0 above the diagonal
  }
}

// ---------------------------------------------------------------- ctx = probs @ V
// grid (s, h, b); block 64 (one lane per d)
__global__ __launch_bounds__(64)
void ctx_kernel(const float* __restrict__ probs, const float* __restrict__ qkv,
                float* __restrict__ ctx) {
  const int s = blockIdx.x, h = blockIdx.y, b = blockIdx.z;
  const int d = threadIdx.x;
  __shared__ float as[256];
  const float* prow = probs + (((size_t)b * NH + h) * NS + s) * NS;
  float acc = 0.f;
  for (int t0 = 0; t0 <= s; t0 += 256) {
    const int chunk = min(256, s + 1 - t0);
    for (int i = d; i < 256; i += 64)
      as[i] = (t0 + i <= s) ? prow[t0 + i] : 0.f;
    __syncthreads();
    for (int tt = 0; tt < chunk; ++tt)
      acc += as[tt] * qkv[(size_t)(b * NS + t0 + tt) * QKVLD + 2 * ND + h * NDK + d];
    __syncthreads();
  }
  ctx[((size_t)(b * NS + s) * NH + h) * NDK + d] = acc;
}

// ---------------------------------------------------------------- residual add + LayerNorm (in place on x)
__global__ __launch_bounds__(256)
void add_ln_kernel(float* __restrict__ x, const float* __restrict__ y,
                   const float* __restrict__ g, const float* __restrict__ bb) {
  const int row = blockIdx.x, tid = threadIdx.x;
  const size_t base = (size_t)row * ND;
  float v0 = x[base + tid], v1 = x[base + tid + 256];
  if (y) { v0 += y[base + tid]; v1 += y[base + tid + 256]; }
  __shared__ float red[256];
  red[tid] = v0 + v1; __syncthreads();
  for (int o = 128; o > 0; o >>= 1) {
    if (tid < o) red[tid] += red[tid + o];
    __syncthreads();
  }
  const float mean = red[0] * (1.f / (float)ND);
  __syncthreads();
  const float d0 = v0 - mean, d1 = v1 - mean;
  red[tid] = d0 * d0 + d1 * d1; __syncthreads();
  for (int o = 128; o > 0; o >>= 1) {
    if (tid < o) red[tid] += red[tid + o];
    __syncthreads();
  }
  const float inv = 1.f / sqrtf(red[0] * (1.f / (float)ND) + 1e-5f);
  x[base + tid]       = d0 * inv * g[tid]       + bb[tid];
  x[base + tid + 256] = d1 * inv * g[tid + 256] + bb[tid + 256];
}

// ---------------------------------------------------------------- launch
extern "C" void kernel_launch(void* const* d_in, const int* in_sizes, int n_in,
                              void* d_out, int out_size, void* d_ws, size_t ws_size,
                              hipStream_t stream) {
  const int*   tokens  = (const int*)d_in[0];
  const float* tok_emb = (const float*)d_in[1];
  const float* Wq = (const float*)d_in[2];
  const float* bq = (const float*)d_in[3];
  const float* Wk = (const float*)d_in[4];
  const float* bk = (const float*)d_in[5];
  const float* Wv = (const float*)d_in[6];
  const float* bv = (const float*)d_in[7];
  const float* Wo = (const float*)d_in[8];
  const float* bo = (const float*)d_in[9];
  const float* ln1_g = (const float*)d_in[10];
  const float* ln1_b = (const float*)d_in[11];
  const float* W1 = (const float*)d_in[12];
  const float* b1 = (const float*)d_in[13];
  const float* W2 = (const float*)d_in[14];
  const float* b2 = (const float*)d_in[15];
  const float* ln2_g = (const float*)d_in[16];
  const float* ln2_b = (const float*)d_in[17];
  const float* lnf_g = (const float*)d_in[18];
  const float* lnf_b = (const float*)d_in[19];
  const float* Wout = (const float*)d_in[20];
  const float* bout = (const float*)d_in[21];

  float* logits   = (float*)d_out;                               // [B,S,V]
  float* attn_all = (float*)d_out + (size_t)NB * NS * NV;        // [L,B,H,S,S]

  float* ws = (float*)d_ws;
  const size_t U = (size_t)MROWS * ND;      // 1,048,576 floats
  float* x   = ws;                          // [M, 512]
  float* qkv = ws + U;                      // [M, 1536]
  float* ctx = ws + 4 * U;                  // [M, 512]
  float* tmp = ws + 5 * U;                  // [M, 512]
  float* h   = ws + U;                      // [M, 2048] overlays qkv+ctx

  const int M = MROWS;

  embed_kernel<<<M, 256, 0, stream>>>(tokens, tok_emb, x);

  const dim3 gQKV(M / 128, 12);             // 3 mats x 4 n-tiles
  const dim3 gProj(M / 128, 4);
  const dim3 gFF1(M / 128, 16);
  const dim3 gOut(M / 128, NV / 128);       // (16, 250)
  const dim3 gAttn(NS, NH, NB);

  for (int l = 0; l < NL; ++l) {
    const float* Wq_l = Wq + (size_t)l * ND * ND;
    const float* Wk_l = Wk + (size_t)l * ND * ND;
    const float* Wv_l = Wv + (size_t)l * ND * ND;
    const float* Wo_l = Wo + (size_t)l * ND * ND;
    const float* W1_l = W1 + (size_t)l * ND * NDFF;
    const float* W2_l = W2 + (size_t)l * NDFF * ND;

    gemm_mfma<0><<<gQKV, 256, 0, stream>>>(x, Wq_l, Wk_l, Wv_l,
                                           bq + l * ND, bk + l * ND, bv + l * ND,
                                           qkv, ND, ND, QKVLD, 4);

    float* probs_l = attn_all + (size_t)l * NB * NH * NS * NS;
    attn_kernel<<<gAttn, 256, 0, stream>>>(qkv, probs_l);
    ctx_kernel<<<gAttn, 64, 0, stream>>>(probs_l, qkv, ctx);

    gemm_mfma<0><<<gProj, 256, 0, stream>>>(ctx, Wo_l, Wo_l, Wo_l,
                                            bo + l * ND, bo + l * ND, bo + l * ND,
                                            tmp, ND, ND, ND, 4);
    add_ln_kernel<<<M, 256, 0, stream>>>(x, tmp, ln1_g + l * ND, ln1_b + l * ND);

    gemm_mfma<1><<<gFF1, 256, 0, stream>>>(x, W1_l, W1_l, W1_l,
                                           b1 + l * NDFF, b1 + l * NDFF, b1 + l * NDFF,
                                           h, NDFF, ND, NDFF, 16);
    gemm_mfma<0><<<gProj, 256, 0, stream>>>(h, W2_l, W2_l, W2_l,
                                            b2 + l * ND, b2 + l * ND, b2 + l * ND,
                                            tmp, ND, NDFF, ND, 4);
    add_ln_kernel<<<M, 256, 0, stream>>>(x, tmp, ln2_g + l * ND, ln2_b + l * ND);
  }

  add_ln_kernel<<<M, 256, 0, stream>>>(x, nullptr, lnf_g, lnf_b);

  gemm_mfma<0><<<gOut, 256, 0, stream>>>(x, Wout, Wout, Wout, bout, bout, bout,
                                         logits, NV, ND, NV, 250);
}

// Round 3
// 1567.893 us; speedup vs baseline: 4.2008x; 2.2398x over previous
//
#include <hip/hip_runtime.h>
#include <math.h>

#define NB 2
#define NS 1024
#define NH 8
#define NDK 64
#define ND 512
#define NDFF 2048
#define NV 32000
#define NL 6
#define MROWS (NB * NS)
#define QKVLD (3 * ND)   // 1536
#define QBLK 16

using bf16_t = __bf16;
using bf16x4 = __attribute__((ext_vector_type(4))) __bf16;
using bf16x8 = __attribute__((ext_vector_type(8))) __bf16;
using f32x4  = __attribute__((ext_vector_type(4))) float;

// ---------------------------------------------------------------- embed
__global__ void embed_kernel(const int* __restrict__ tokens,
                             const float* __restrict__ emb,
                             float* __restrict__ x) {
  const int row = blockIdx.x;            // b*NS + s
  const int s = row & (NS - 1);
  const int tok = tokens[row];
  const int tid = threadIdx.x;
  const float SQRTD = 22.627416997969522f;             // sqrt(512)
  const float C = -9.210340371976184f / (float)ND;     // -ln(10000)/D
#pragma unroll
  for (int i = 0; i < 2; ++i) {
    const int d = tid + i * 256;
    const int pair = d >> 1;
    const float div = expf((float)(2 * pair) * C);
    const float ang = (float)s * div;
    const float pe = (d & 1) ? cosf(ang) : sinf(ang);
    x[(size_t)row * ND + d] = emb[(size_t)tok * ND + d] * SQRTD + pe;
  }
}

// ---------------------------------------------------------------- MFMA GEMM
// C[:, mat*N + 0..N) = A[M,K] @ Wmat[K,N] + bias_mat ; ldc = row stride of C.
template <int ACT>
__global__ __launch_bounds__(256)
void gemm_mfma(const float* __restrict__ A,
               const float* __restrict__ W0, const float* __restrict__ W1,
               const float* __restrict__ W2,
               const float* __restrict__ B0, const float* __restrict__ B1,
               const float* __restrict__ B2,
               float* __restrict__ C, int N, int K, int ldc, int nbm) {
  const int mat = blockIdx.y / nbm;
  const int nb  = blockIdx.y % nbm;
  const float* W    = (mat == 0) ? W0 : (mat == 1) ? W1 : W2;
  const float* bias = (mat == 0) ? B0 : (mat == 1) ? B1 : B2;
  const int m0 = blockIdx.x * 128;
  const int n0 = nb * 128;

  __shared__ bf16_t As[128 * 40];      // [m][k] rows padded 32->40
  __shared__ bf16_t Bs[4 * 128 * 8];   // [kc][n][8]

  const int tid  = threadIdx.x;
  const int lane = tid & 63;
  const int wave = tid >> 6;
  const int wm = wave >> 1, wn = wave & 1;
  const int lrow = lane & 15, kc = lane >> 4;

  const int a_kq = tid & 7, a_m = tid >> 3;     // A staging
  const int b_n = tid & 127, b_h = tid >> 7;    // B staging

  f32x4 acc[4][4] = {};

  for (int k0 = 0; k0 < K; k0 += 32) {
#pragma unroll
    for (int r = 0; r < 4; ++r) {
      const int m = a_m + r * 32;
      const float4 av = *(const float4*)&A[(size_t)(m0 + m) * K + k0 + a_kq * 4];
      bf16x4 p;
      p[0] = (bf16_t)av.x; p[1] = (bf16_t)av.y;
      p[2] = (bf16_t)av.z; p[3] = (bf16_t)av.w;
      *(bf16x4*)&As[m * 40 + a_kq * 4] = p;
    }
#pragma unroll
    for (int c = 0; c < 2; ++c) {
      const int kcc = b_h * 2 + c;
      bf16x8 p;
#pragma unroll
      for (int j = 0; j < 8; ++j)
        p[j] = (bf16_t)W[(size_t)(k0 + kcc * 8 + j) * N + n0 + b_n];
      *(bf16x8*)&Bs[(kcc * 128 + b_n) * 8] = p;
    }
    __syncthreads();

    bf16x8 af[4], bfv[4];
#pragma unroll
    for (int m = 0; m < 4; ++m)
      af[m] = *(const bf16x8*)&As[(wm * 64 + m * 16 + lrow) * 40 + kc * 8];
#pragma unroll
    for (int n = 0; n < 4; ++n)
      bfv[n] = *(const bf16x8*)&Bs[(kc * 128 + wn * 64 + n * 16 + lrow) * 8];
#pragma unroll
    for (int m = 0; m < 4; ++m)
#pragma unroll
      for (int n = 0; n < 4; ++n)
        acc[m][n] = __builtin_amdgcn_mfma_f32_16x16x32_bf16(af[m], bfv[n], acc[m][n], 0, 0, 0);
    __syncthreads();
  }

  const int crow0 = (lane >> 4) * 4, ccol = lane & 15;
#pragma unroll
  for (int m = 0; m < 4; ++m) {
#pragma unroll
    for (int n = 0; n < 4; ++n) {
      const int ncl = n0 + wn * 64 + n * 16 + ccol;
      const float bv = bias[ncl];
      const size_t ccol_g = (size_t)mat * N + ncl;
#pragma unroll
      for (int i = 0; i < 4; ++i) {
        const int row = m0 + wm * 64 + m * 16 + crow0 + i;
        float v = acc[m][n][i] + bv;
        if (ACT == 1) v = 0.5f * v * (1.0f + erff(v * 0.7071067811865476f));
        C[(size_t)row * ldc + ccol_g] = v;
      }
    }
  }
}

// ---------------------------------------------------------------- attn scores + softmax (MFMA)
// grid (S/QBLK, H, B), block 256. Writes softmaxed probs (f32) for 16 q-rows.
__global__ __launch_bounds__(256)
void attn_scores_kernel(const float* __restrict__ qkv, float* __restrict__ probs) {
  const int q0 = blockIdx.x * QBLK;
  const int h = blockIdx.y, b = blockIdx.z;
  const int NTT = (q0 + QBLK + 127) >> 7;          // causal 128-t tiles
  const int tid = threadIdx.x;
  const int lane = tid & 63, wq = tid >> 6;
  const int lrow = lane & 15, g = lane >> 4;

  __shared__ bf16_t Qs[QBLK][72];
  __shared__ bf16_t Ks[128][72];
  __shared__ float sMax[4][QBLK];
  __shared__ float sSum[4][QBLK];

  {  // stage Q (16x64 f32 -> bf16)
    const int r = tid >> 4, c4 = (tid & 15) * 4;
    const float4 qv = *(const float4*)&qkv[((size_t)(b * NS + q0 + r)) * QKVLD + h * NDK + c4];
    bf16x4 p; p[0] = (bf16_t)qv.x; p[1] = (bf16_t)qv.y; p[2] = (bf16_t)qv.z; p[3] = (bf16_t)qv.w;
    *(bf16x4*)&Qs[r][c4] = p;
  }
  __syncthreads();
  const bf16x8 aq0 = *(const bf16x8*)&Qs[lrow][g * 8];
  const bf16x8 aq1 = *(const bf16x8*)&Qs[lrow][32 + g * 8];

  f32x4 sc[16] = {};   // per-lane scores: [tile*2+sub][row i]

#pragma unroll
  for (int tile = 0; tile < 8; ++tile) {
    if (tile < NTT) {
      const int t0 = tile * 128;
#pragma unroll
      for (int p = 0; p < 8; ++p) {            // stage K tile (128x64)
        const int r = (tid >> 4) + p * 16;
        const int c4 = (tid & 15) * 4;
        const float4 kv = *(const float4*)&qkv[((size_t)(b * NS + t0 + r)) * QKVLD + ND + h * NDK + c4];
        bf16x4 pk; pk[0] = (bf16_t)kv.x; pk[1] = (bf16_t)kv.y; pk[2] = (bf16_t)kv.z; pk[3] = (bf16_t)kv.w;
        *(bf16x4*)&Ks[r][c4] = pk;
      }
      __syncthreads();
#pragma unroll
      for (int sub = 0; sub < 2; ++sub) {
        const int tb = wq * 32 + sub * 16;
        const bf16x8 bk0 = *(const bf16x8*)&Ks[tb + lrow][g * 8];
        const bf16x8 bk1 = *(const bf16x8*)&Ks[tb + lrow][32 + g * 8];
        sc[tile * 2 + sub] = __builtin_amdgcn_mfma_f32_16x16x32_bf16(aq0, bk0, sc[tile * 2 + sub], 0, 0, 0);
        sc[tile * 2 + sub] = __builtin_amdgcn_mfma_f32_16x16x32_bf16(aq1, bk1, sc[tile * 2 + sub], 0, 0, 0);
      }
      __syncthreads();
    }
  }

  // mask + scale in place, per-row max
  float mrow[4], srow[4];
#pragma unroll
  for (int i = 0; i < 4; ++i) mrow[i] = -1e30f;
#pragma unroll
  for (int tile = 0; tile < 8; ++tile)
#pragma unroll
    for (int sub = 0; sub < 2; ++sub) {
      const int t = tile * 128 + wq * 32 + sub * 16 + lrow;
#pragma unroll
      for (int i = 0; i < 4; ++i) {
        const int q = q0 + g * 4 + i;
        const float v = (t <= q) ? sc[tile * 2 + sub][i] * 0.125f : -1e30f;
        sc[tile * 2 + sub][i] = v;
        mrow[i] = fmaxf(mrow[i], v);
      }
    }
#pragma unroll
  for (int i = 0; i < 4; ++i) {
    mrow[i] = fmaxf(mrow[i], __shfl_xor(mrow[i], 1));
    mrow[i] = fmaxf(mrow[i], __shfl_xor(mrow[i], 2));
    mrow[i] = fmaxf(mrow[i], __shfl_xor(mrow[i], 4));
    mrow[i] = fmaxf(mrow[i], __shfl_xor(mrow[i], 8));
  }
  if (lrow == 0) {
#pragma unroll
    for (int i = 0; i < 4; ++i) sMax[wq][g * 4 + i] = mrow[i];
  }
  __syncthreads();
#pragma unroll
  for (int i = 0; i < 4; ++i) {
    const int r = g * 4 + i;
    mrow[i] = fmaxf(fmaxf(sMax[0][r], sMax[1][r]), fmaxf(sMax[2][r], sMax[3][r]));
    srow[i] = 0.f;
  }
  // exp in place + per-row sum
#pragma unroll
  for (int tile = 0; tile < 8; ++tile)
#pragma unroll
    for (int sub = 0; sub < 2; ++sub)
#pragma unroll
      for (int i = 0; i < 4; ++i) {
        const float e = expf(sc[tile * 2 + sub][i] - mrow[i]);
        sc[tile * 2 + sub][i] = e;
        srow[i] += e;
      }
#pragma unroll
  for (int i = 0; i < 4; ++i) {
    srow[i] += __shfl_xor(srow[i], 1);
    srow[i] += __shfl_xor(srow[i], 2);
    srow[i] += __shfl_xor(srow[i], 4);
    srow[i] += __shfl_xor(srow[i], 8);
  }
  if (lrow == 0) {
#pragma unroll
    for (int i = 0; i < 4; ++i) sSum[wq][g * 4 + i] = srow[i];
  }
  __syncthreads();
  float inv[4];
#pragma unroll
  for (int i = 0; i < 4; ++i) {
    const int r = g * 4 + i;
    inv[i] = 1.f / (sSum[0][r] + sSum[1][r] + sSum[2][r] + sSum[3][r]);
  }

  // write probs
  const size_t rowbase = ((size_t)(b * NH + h)) * NS;
#pragma unroll
  for (int tile = 0; tile < 8; ++tile) {
    if (tile < NTT) {
#pragma unroll
      for (int sub = 0; sub < 2; ++sub) {
        const int t = tile * 128 + wq * 32 + sub * 16 + lrow;
#pragma unroll
        for (int i = 0; i < 4; ++i) {
          const int q = q0 + g * 4 + i;
          probs[(rowbase + q) * NS + t] = sc[tile * 2 + sub][i] * inv[i];
        }
      }
    }
  }
  // zero-fill t in [NTT*128, NS)
  const int z0 = NTT * 128;
  const int zc = (NS - z0) >> 2;
  const float4 zf = {0.f, 0.f, 0.f, 0.f};
  for (int idx = tid; idx < QBLK * zc; idx += 256) {
    const int r = idx / zc, c = (idx - r * zc) * 4;
    *(float4*)&probs[(rowbase + q0 + r) * NS + z0 + c] = zf;
  }
}

// ---------------------------------------------------------------- ctx = P @ V (MFMA, causal K-range)
// grid (S/128, H, B), block 256. ctx written as [M][512] at col h*64+dk.
__global__ __launch_bounds__(256)
void attn_pv_kernel(const float* __restrict__ probs, const float* __restrict__ qkv,
                    float* __restrict__ ctx) {
  const int m0 = blockIdx.x * 128;
  const int h = blockIdx.y, b = blockIdx.z;
  const int tid = threadIdx.x;
  const int lane = tid & 63, w = tid >> 6;
  const int lrow = lane & 15, g = lane >> 4;

  __shared__ bf16_t Ps[128][36];
  __shared__ bf16_t Vs[64][40];

  const int nk = (m0 + 128) >> 5;
  f32x4 acc[2][4] = {};
  const size_t pbase = ((size_t)(b * NH + h)) * NS;

  for (int ks = 0; ks < nk; ++ks) {
    const int t0 = ks * 32;
#pragma unroll
    for (int p = 0; p < 4; ++p) {            // stage P 128x32
      const int r = (tid >> 3) + p * 32;
      const int c = (tid & 7) * 4;
      const float4 pv = *(const float4*)&probs[(pbase + m0 + r) * NS + t0 + c];
      bf16x4 pk; pk[0] = (bf16_t)pv.x; pk[1] = (bf16_t)pv.y; pk[2] = (bf16_t)pv.z; pk[3] = (bf16_t)pv.w;
      *(bf16x4*)&Ps[r][c] = pk;
    }
#pragma unroll
    for (int p = 0; p < 2; ++p) {            // stage V 32x64 transposed
      const int tt = (tid >> 4) + p * 16;
      const int dk = (tid & 15) * 4;
      const float4 vv = *(const float4*)&qkv[((size_t)(b * NS + t0 + tt)) * QKVLD + 2 * ND + h * NDK + dk];
      Vs[dk + 0][tt] = (bf16_t)vv.x;
      Vs[dk + 1][tt] = (bf16_t)vv.y;
      Vs[dk + 2][tt] = (bf16_t)vv.z;
      Vs[dk + 3][tt] = (bf16_t)vv.w;
    }
    __syncthreads();
    bf16x8 pa[2], vb[4];
#pragma unroll
    for (int mf = 0; mf < 2; ++mf)
      pa[mf] = *(const bf16x8*)&Ps[w * 32 + mf * 16 + lrow][g * 8];
#pragma unroll
    for (int nf = 0; nf < 4; ++nf)
      vb[nf] = *(const bf16x8*)&Vs[nf * 16 + lrow][g * 8];
#pragma unroll
    for (int mf = 0; mf < 2; ++mf)
#pragma unroll
      for (int nf = 0; nf < 4; ++nf)
        acc[mf][nf] = __builtin_amdgcn_mfma_f32_16x16x32_bf16(pa[mf], vb[nf], acc[mf][nf], 0, 0, 0);
    __syncthreads();
  }

#pragma unroll
  for (int mf = 0; mf < 2; ++mf)
#pragma unroll
    for (int nf = 0; nf < 4; ++nf)
#pragma unroll
      for (int i = 0; i < 4; ++i) {
        const int row = m0 + w * 32 + mf * 16 + g * 4 + i;
        const int dk = nf * 16 + lrow;
        ctx[((size_t)(b * NS + row)) * ND + h * NDK + dk] = acc[mf][nf][i];
      }
}

// ---------------------------------------------------------------- residual add + LayerNorm (in place on x)
__global__ __launch_bounds__(256)
void add_ln_kernel(float* __restrict__ x, const float* __restrict__ y,
                   const float* __restrict__ g, const float* __restrict__ bb) {
  const int row = blockIdx.x, tid = threadIdx.x;
  const size_t base = (size_t)row * ND;
  float v0 = x[base + tid], v1 = x[base + tid + 256];
  if (y) { v0 += y[base + tid]; v1 += y[base + tid + 256]; }
  __shared__ float red[256];
  red[tid] = v0 + v1; __syncthreads();
  for (int o = 128; o > 0; o >>= 1) {
    if (tid < o) red[tid] += red[tid + o];
    __syncthreads();
  }
  const float mean = red[0] * (1.f / (float)ND);
  __syncthreads();
  const float d0 = v0 - mean, d1 = v1 - mean;
  red[tid] = d0 * d0 + d1 * d1; __syncthreads();
  for (int o = 128; o > 0; o >>= 1) {
    if (tid < o) red[tid] += red[tid + o];
    __syncthreads();
  }
  const float inv = 1.f / sqrtf(red[0] * (1.f / (float)ND) + 1e-5f);
  x[base + tid]       = d0 * inv * g[tid]       + bb[tid];
  x[base + tid + 256] = d1 * inv * g[tid + 256] + bb[tid + 256];
}

// ---------------------------------------------------------------- launch
extern "C" void kernel_launch(void* const* d_in, const int* in_sizes, int n_in,
                              void* d_out, int out_size, void* d_ws, size_t ws_size,
                              hipStream_t stream) {
  const int*   tokens  = (const int*)d_in[0];
  const float* tok_emb = (const float*)d_in[1];
  const float* Wq = (const float*)d_in[2];
  const float* bq = (const float*)d_in[3];
  const float* Wk = (const float*)d_in[4];
  const float* bk = (const float*)d_in[5];
  const float* Wv = (const float*)d_in[6];
  const float* bv = (const float*)d_in[7];
  const float* Wo = (const float*)d_in[8];
  const float* bo = (const float*)d_in[9];
  const float* ln1_g = (const float*)d_in[10];
  const float* ln1_b = (const float*)d_in[11];
  const float* W1 = (const float*)d_in[12];
  const float* b1 = (const float*)d_in[13];
  const float* W2 = (const float*)d_in[14];
  const float* b2 = (const float*)d_in[15];
  const float* ln2_g = (const float*)d_in[16];
  const float* ln2_b = (const float*)d_in[17];
  const float* lnf_g = (const float*)d_in[18];
  const float* lnf_b = (const float*)d_in[19];
  const float* Wout = (const float*)d_in[20];
  const float* bout = (const float*)d_in[21];

  float* logits   = (float*)d_out;                               // [B,S,V]
  float* attn_all = (float*)d_out + (size_t)NB * NS * NV;        // [L,B,H,S,S]

  float* ws = (float*)d_ws;
  const size_t U = (size_t)MROWS * ND;      // 1,048,576 floats
  float* x   = ws;                          // [M, 512]
  float* qkv = ws + U;                      // [M, 1536]
  float* ctx = ws + 4 * U;                  // [M, 512]
  float* tmp = ws + 5 * U;                  // [M, 512]
  float* h   = ws + U;                      // [M, 2048] overlays qkv+ctx

  const int M = MROWS;

  embed_kernel<<<M, 256, 0, stream>>>(tokens, tok_emb, x);

  const dim3 gQKV(M / 128, 12);             // 3 mats x 4 n-tiles
  const dim3 gProj(M / 128, 4);
  const dim3 gFF1(M / 128, 16);
  const dim3 gOut(M / 128, NV / 128);       // (16, 250)
  const dim3 gScores(NS / QBLK, NH, NB);    // (64, 8, 2)
  const dim3 gPV(NS / 128, NH, NB);         // (8, 8, 2)

  for (int l = 0; l < NL; ++l) {
    const float* Wq_l = Wq + (size_t)l * ND * ND;
    const float* Wk_l = Wk + (size_t)l * ND * ND;
    const float* Wv_l = Wv + (size_t)l * ND * ND;
    const float* Wo_l = Wo + (size_t)l * ND * ND;
    const float* W1_l = W1 + (size_t)l * ND * NDFF;
    const float* W2_l = W2 + (size_t)l * NDFF * ND;

    gemm_mfma<0><<<gQKV, 256, 0, stream>>>(x, Wq_l, Wk_l, Wv_l,
                                           bq + l * ND, bk + l * ND, bv + l * ND,
                                           qkv, ND, ND, QKVLD, 4);

    float* probs_l = attn_all + (size_t)l * NB * NH * NS * NS;
    attn_scores_kernel<<<gScores, 256, 0, stream>>>(qkv, probs_l);
    attn_pv_kernel<<<gPV, 256, 0, stream>>>(probs_l, qkv, ctx);

    gemm_mfma<0><<<gProj, 256, 0, stream>>>(ctx, Wo_l, Wo_l, Wo_l,
                                            bo + l * ND, bo + l * ND, bo + l * ND,
                                            tmp, ND, ND, ND, 4);
    add_ln_kernel<<<M, 256, 0, stream>>>(x, tmp, ln1_g + l * ND, ln1_b + l * ND);

    gemm_mfma<1><<<gFF1, 256, 0, stream>>>(x, W1_l, W1_l, W1_l,
                                           b1 + l * NDFF, b1 + l * NDFF, b1 + l * NDFF,
                                           h, NDFF, ND, NDFF, 16);
    gemm_mfma<0><<<gProj, 256, 0, stream>>>(h, W2_l, W2_l, W2_l,
                                            b2 + l * ND, b2 + l * ND, b2 + l * ND,
                                            tmp, ND, NDFF, ND, 4);
    add_ln_kernel<<<M, 256, 0, stream>>>(x, tmp, ln2_g + l * ND, ln2_b + l * ND);
  }

  add_ln_kernel<<<M, 256, 0, stream>>>(x, nullptr, lnf_g, lnf_b);

  gemm_mfma<0><<<gOut, 256, 0, stream>>>(x, Wout, Wout, Wout, bout, bout, bout,
                                         logits, NV, ND, NV, 250);
}

// Round 4
// 1176.945 us; speedup vs baseline: 5.5962x; 1.3322x over previous
//
#include <hip/hip_runtime.h>
#include <math.h>

#define NB 2
#define NS 1024
#define NH 8
#define NDK 64
#define ND 512
#define NDFF 2048
#define NV 32000
#define NL 6
#define MROWS (NB * NS)
#define QKVLD (3 * ND)   // 1536
#define QBLK 16

using bf16_t = __bf16;
using bf16x4 = __attribute__((ext_vector_type(4))) __bf16;
using bf16x8 = __attribute__((ext_vector_type(8))) __bf16;
using f32x4  = __attribute__((ext_vector_type(4))) float;

__device__ __forceinline__ void gload_lds16(const bf16_t* g, bf16_t* l) {
  __builtin_amdgcn_global_load_lds(
      (const __attribute__((address_space(1))) void*)g,
      (__attribute__((address_space(3))) void*)l, 16, 0, 0);
}

// ---------------------------------------------------------------- embed (+ optional bf16 copy)
__global__ void embed_kernel(const int* __restrict__ tokens,
                             const float* __restrict__ emb,
                             float* __restrict__ x, bf16_t* __restrict__ xb) {
  const int row = blockIdx.x;            // b*NS + s
  const int s = row & (NS - 1);
  const int tok = tokens[row];
  const int tid = threadIdx.x;
  const float SQRTD = 22.627416997969522f;             // sqrt(512)
  const float C = -9.210340371976184f / (float)ND;     // -ln(10000)/D
#pragma unroll
  for (int i = 0; i < 2; ++i) {
    const int d = tid + i * 256;
    const int pair = d >> 1;
    const float div = expf((float)(2 * pair) * C);
    const float ang = (float)s * div;
    const float pe = (d & 1) ? cosf(ang) : sinf(ang);
    const float v = emb[(size_t)tok * ND + d] * SQRTD + pe;
    x[(size_t)row * ND + d] = v;
    if (xb) xb[(size_t)row * ND + d] = (bf16_t)v;
  }
}

// ---------------------------------------------------------------- residual add + LayerNorm (+ optional bf16 copy)
__global__ __launch_bounds__(256)
void add_ln_kernel(float* __restrict__ x, const float* __restrict__ y,
                   const float* __restrict__ g, const float* __restrict__ bb,
                   bf16_t* __restrict__ xb) {
  const int row = blockIdx.x, tid = threadIdx.x;
  const size_t base = (size_t)row * ND;
  float v0 = x[base + tid], v1 = x[base + tid + 256];
  if (y) { v0 += y[base + tid]; v1 += y[base + tid + 256]; }
  __shared__ float red[256];
  red[tid] = v0 + v1; __syncthreads();
  for (int o = 128; o > 0; o >>= 1) {
    if (tid < o) red[tid] += red[tid + o];
    __syncthreads();
  }
  const float mean = red[0] * (1.f / (float)ND);
  __syncthreads();
  const float d0 = v0 - mean, d1 = v1 - mean;
  red[tid] = d0 * d0 + d1 * d1; __syncthreads();
  for (int o = 128; o > 0; o >>= 1) {
    if (tid < o) red[tid] += red[tid + o];
    __syncthreads();
  }
  const float inv = 1.f / sqrtf(red[0] * (1.f / (float)ND) + 1e-5f);
  const float o0 = d0 * inv * g[tid]       + bb[tid];
  const float o1 = d1 * inv * g[tid + 256] + bb[tid + 256];
  x[base + tid] = o0;
  x[base + tid + 256] = o1;
  if (xb) { xb[base + tid] = (bf16_t)o0; xb[base + tid + 256] = (bf16_t)o1; }
}

// ---------------------------------------------------------------- transpose+convert: src f32 [K][N] -> dst bf16 [N][K]
__global__ __launch_bounds__(256)
void transpose_bf16_kernel(const float* __restrict__ src, bf16_t* __restrict__ dst,
                           int K, int N, size_t sstride, size_t dstride) {
  __shared__ bf16_t T[64][72];
  const float* s = src + (size_t)blockIdx.z * sstride;
  bf16_t* d = dst + (size_t)blockIdx.z * dstride;
  const int n0 = blockIdx.x * 64, k0 = blockIdx.y * 64;
  const int tid = threadIdx.x;
#pragma unroll
  for (int it = 0; it < 4; ++it) {
    const int k = (tid >> 4) + it * 16;
    const int c = (tid & 15) * 4;
    const float4 v = *(const float4*)&s[(size_t)(k0 + k) * N + n0 + c];
    T[c + 0][k] = (bf16_t)v.x;
    T[c + 1][k] = (bf16_t)v.y;
    T[c + 2][k] = (bf16_t)v.z;
    T[c + 3][k] = (bf16_t)v.w;
  }
  __syncthreads();
  const int n = tid >> 2, kk = (tid & 3) * 16;
  bf16x8 a = *(const bf16x8*)&T[n][kk];
  bf16x8 b = *(const bf16x8*)&T[n][kk + 8];
  *(bf16x8*)&d[(size_t)(n0 + n) * K + k0 + kk] = a;
  *(bf16x8*)&d[(size_t)(n0 + n) * K + k0 + kk + 8] = b;
}

// ---------------------------------------------------------------- NEW GEMM: A bf16 [M][lda], Wt bf16 [N][K] (k-major both)
// C = A @ Wt^T + bias ; bias select: sel = col>>bshift, idx = col&bmask.
// grid (M/128, N/128). global_load_lds staging, XOR-swizzled LDS.
template <int ACT, int OUTBF>
__global__ __launch_bounds__(256)
void gemm_bt(const bf16_t* __restrict__ A, const bf16_t* __restrict__ Wt,
             const float* __restrict__ B0, const float* __restrict__ B1,
             const float* __restrict__ B2,
             void* __restrict__ Cout, int N, int K, int lda, int ldc,
             int bshift, int bmask) {
  __shared__ bf16_t As[128 * 32];
  __shared__ bf16_t Bs[128 * 32];
  const int tid = threadIdx.x, lane = tid & 63, w = tid >> 6;
  const int wm = w >> 1, wn = w & 1;
  const int lrow = lane & 15, kc = lane >> 4;
  const int m0 = blockIdx.x * 128, n0 = blockIdx.y * 128;
  const int srow_l = lane >> 2;          // 0..15
  const int sslot = lane & 3;

  f32x4 acc[4][4] = {};

  for (int k0 = 0; k0 < K; k0 += 32) {
#pragma unroll
    for (int t = 0; t < 2; ++t) {
      const int row = t * 64 + w * 16 + srow_l;              // tile-local
      const int gs = sslot ^ ((row >> 1) & 3);               // inverse swizzle on source
      gload_lds16(&A[(size_t)(m0 + row) * lda + k0 + gs * 8], &As[(t * 64 + w * 16) * 32]);
      gload_lds16(&Wt[(size_t)(n0 + row) * K + k0 + gs * 8], &Bs[(t * 64 + w * 16) * 32]);
    }
    __syncthreads();

    bf16x8 af[4], bf[4];
#pragma unroll
    for (int m = 0; m < 4; ++m) {
      const int r = wm * 64 + m * 16 + lrow;
      af[m] = *(const bf16x8*)&As[r * 32 + ((kc ^ ((r >> 1) & 3)) * 8)];
    }
#pragma unroll
    for (int n = 0; n < 4; ++n) {
      const int r = wn * 64 + n * 16 + lrow;
      bf[n] = *(const bf16x8*)&Bs[r * 32 + ((kc ^ ((r >> 1) & 3)) * 8)];
    }
#pragma unroll
    for (int m = 0; m < 4; ++m)
#pragma unroll
      for (int n = 0; n < 4; ++n)
        acc[m][n] = __builtin_amdgcn_mfma_f32_16x16x32_bf16(af[m], bf[n], acc[m][n], 0, 0, 0);
    __syncthreads();
  }

  const int crow0 = (lane >> 4) * 4, ccol = lane & 15;
#pragma unroll
  for (int m = 0; m < 4; ++m) {
#pragma unroll
    for (int n = 0; n < 4; ++n) {
      const int ncl = n0 + wn * 64 + n * 16 + ccol;
      const int sel = ncl >> bshift;
      const float bv = ((sel == 0) ? B0 : (sel == 1) ? B1 : B2)[ncl & bmask];
#pragma unroll
      for (int i = 0; i < 4; ++i) {
        const int row = m0 + wm * 64 + m * 16 + crow0 + i;
        float v = acc[m][n][i] + bv;
        if (ACT == 1) v = 0.5f * v * (1.0f + erff(v * 0.7071067811865476f));
        if (OUTBF) ((bf16_t*)Cout)[(size_t)row * ldc + ncl] = (bf16_t)v;
        else       ((float*)Cout)[(size_t)row * ldc + ncl] = v;
      }
    }
  }
}

// ---------------------------------------------------------------- NEW attn scores + softmax (bf16 qkv)
__global__ __launch_bounds__(256)
void attn_scores_b(const bf16_t* __restrict__ qkv, float* __restrict__ probs) {
  const int q0 = blockIdx.x * QBLK;
  const int h = blockIdx.y, b = blockIdx.z;
  const int NTT = (q0 + QBLK + 127) >> 7;
  const int tid = threadIdx.x;
  const int lane = tid & 63, wq = tid >> 6;
  const int lrow = lane & 15, g = lane >> 4;

  __shared__ bf16_t Qs[QBLK][72];
  __shared__ bf16_t Ks[128][72];
  __shared__ float sMax[4][QBLK];
  __shared__ float sSum[4][QBLK];

  if (tid < 128) {
    const int r = tid >> 3, c8 = (tid & 7) * 8;
    *(bf16x8*)&Qs[r][c8] =
        *(const bf16x8*)&qkv[((size_t)(b * NS + q0 + r)) * QKVLD + h * NDK + c8];
  }
  __syncthreads();
  const bf16x8 aq0 = *(const bf16x8*)&Qs[lrow][g * 8];
  const bf16x8 aq1 = *(const bf16x8*)&Qs[lrow][32 + g * 8];

  f32x4 sc[16] = {};

#pragma unroll
  for (int tile = 0; tile < 8; ++tile) {
    if (tile < NTT) {
      const int t0 = tile * 128;
#pragma unroll
      for (int p = 0; p < 4; ++p) {
        const int r = (tid >> 3) + p * 32;
        const int c8 = (tid & 7) * 8;
        *(bf16x8*)&Ks[r][c8] =
            *(const bf16x8*)&qkv[((size_t)(b * NS + t0 + r)) * QKVLD + ND + h * NDK + c8];
      }
      __syncthreads();
#pragma unroll
      for (int sub = 0; sub < 2; ++sub) {
        const int tb = wq * 32 + sub * 16;
        const bf16x8 bk0 = *(const bf16x8*)&Ks[tb + lrow][g * 8];
        const bf16x8 bk1 = *(const bf16x8*)&Ks[tb + lrow][32 + g * 8];
        sc[tile * 2 + sub] = __builtin_amdgcn_mfma_f32_16x16x32_bf16(aq0, bk0, sc[tile * 2 + sub], 0, 0, 0);
        sc[tile * 2 + sub] = __builtin_amdgcn_mfma_f32_16x16x32_bf16(aq1, bk1, sc[tile * 2 + sub], 0, 0, 0);
      }
      __syncthreads();
    }
  }

  float mrow[4], srow[4];
#pragma unroll
  for (int i = 0; i < 4; ++i) mrow[i] = -1e30f;
#pragma unroll
  for (int tile = 0; tile < 8; ++tile)
#pragma unroll
    for (int sub = 0; sub < 2; ++sub) {
      const int t = tile * 128 + wq * 32 + sub * 16 + lrow;
#pragma unroll
      for (int i = 0; i < 4; ++i) {
        const int q = q0 + g * 4 + i;
        const float v = (t <= q) ? sc[tile * 2 + sub][i] * 0.125f : -1e30f;
        sc[tile * 2 + sub][i] = v;
        mrow[i] = fmaxf(mrow[i], v);
      }
    }
#pragma unroll
  for (int i = 0; i < 4; ++i) {
    mrow[i] = fmaxf(mrow[i], __shfl_xor(mrow[i], 1));
    mrow[i] = fmaxf(mrow[i], __shfl_xor(mrow[i], 2));
    mrow[i] = fmaxf(mrow[i], __shfl_xor(mrow[i], 4));
    mrow[i] = fmaxf(mrow[i], __shfl_xor(mrow[i], 8));
  }
  if (lrow == 0) {
#pragma unroll
    for (int i = 0; i < 4; ++i) sMax[wq][g * 4 + i] = mrow[i];
  }
  __syncthreads();
#pragma unroll
  for (int i = 0; i < 4; ++i) {
    const int r = g * 4 + i;
    mrow[i] = fmaxf(fmaxf(sMax[0][r], sMax[1][r]), fmaxf(sMax[2][r], sMax[3][r]));
    srow[i] = 0.f;
  }
#pragma unroll
  for (int tile = 0; tile < 8; ++tile)
#pragma unroll
    for (int sub = 0; sub < 2; ++sub)
#pragma unroll
      for (int i = 0; i < 4; ++i) {
        const float e = expf(sc[tile * 2 + sub][i] - mrow[i]);
        sc[tile * 2 + sub][i] = e;
        srow[i] += e;
      }
#pragma unroll
  for (int i = 0; i < 4; ++i) {
    srow[i] += __shfl_xor(srow[i], 1);
    srow[i] += __shfl_xor(srow[i], 2);
    srow[i] += __shfl_xor(srow[i], 4);
    srow[i] += __shfl_xor(srow[i], 8);
  }
  if (lrow == 0) {
#pragma unroll
    for (int i = 0; i < 4; ++i) sSum[wq][g * 4 + i] = srow[i];
  }
  __syncthreads();
  float inv[4];
#pragma unroll
  for (int i = 0; i < 4; ++i) {
    const int r = g * 4 + i;
    inv[i] = 1.f / (sSum[0][r] + sSum[1][r] + sSum[2][r] + sSum[3][r]);
  }

  const size_t rowbase = ((size_t)(b * NH + h)) * NS;
#pragma unroll
  for (int tile = 0; tile < 8; ++tile) {
    if (tile < NTT) {
#pragma unroll
      for (int sub = 0; sub < 2; ++sub) {
        const int t = tile * 128 + wq * 32 + sub * 16 + lrow;
#pragma unroll
        for (int i = 0; i < 4; ++i) {
          const int q = q0 + g * 4 + i;
          probs[(rowbase + q) * NS + t] = sc[tile * 2 + sub][i] * inv[i];
        }
      }
    }
  }
  const int z0 = NTT * 128;
  const int zc = (NS - z0) >> 2;
  const float4 zf = {0.f, 0.f, 0.f, 0.f};
  for (int idx = tid; idx < QBLK * zc; idx += 256) {
    const int r = idx / zc, c = (idx - r * zc) * 4;
    *(float4*)&probs[(rowbase + q0 + r) * NS + z0 + c] = zf;
  }
}

// ---------------------------------------------------------------- NEW ctx = P @ V (bf16 V, bf16 ctx out)
__global__ __launch_bounds__(256)
void attn_pv_b(const float* __restrict__ probs, const bf16_t* __restrict__ qkv,
               bf16_t* __restrict__ ctx) {
  const int m0 = blockIdx.x * 128;
  const int h = blockIdx.y, b = blockIdx.z;
  const int tid = threadIdx.x;
  const int lane = tid & 63, w = tid >> 6;
  const int lrow = lane & 15, g = lane >> 4;

  __shared__ bf16_t Ps[128][36];
  __shared__ bf16_t Vs[64][40];

  const int nk = (m0 + 128) >> 5;
  f32x4 acc[2][4] = {};
  const size_t pbase = ((size_t)(b * NH + h)) * NS;

  for (int ks = 0; ks < nk; ++ks) {
    const int t0 = ks * 32;
#pragma unroll
    for (int p = 0; p < 4; ++p) {
      const int r = (tid >> 3) + p * 32;
      const int c = (tid & 7) * 4;
      const float4 pv = *(const float4*)&probs[(pbase + m0 + r) * NS + t0 + c];
      bf16x4 pk; pk[0] = (bf16_t)pv.x; pk[1] = (bf16_t)pv.y; pk[2] = (bf16_t)pv.z; pk[3] = (bf16_t)pv.w;
      *(bf16x4*)&Ps[r][c] = pk;
    }
    {
      const int tt = tid >> 3;           // 0..31
      const int dk8 = (tid & 7) * 8;
      bf16x8 v8 = *(const bf16x8*)&qkv[((size_t)(b * NS + t0 + tt)) * QKVLD + 2 * ND + h * NDK + dk8];
#pragma unroll
      for (int j = 0; j < 8; ++j) Vs[dk8 + j][tt] = v8[j];
    }
    __syncthreads();
    bf16x8 pa[2], vb[4];
#pragma unroll
    for (int mf = 0; mf < 2; ++mf)
      pa[mf] = *(const bf16x8*)&Ps[w * 32 + mf * 16 + lrow][g * 8];
#pragma unroll
    for (int nf = 0; nf < 4; ++nf)
      vb[nf] = *(const bf16x8*)&Vs[nf * 16 + lrow][g * 8];
#pragma unroll
    for (int mf = 0; mf < 2; ++mf)
#pragma unroll
      for (int nf = 0; nf < 4; ++nf)
        acc[mf][nf] = __builtin_amdgcn_mfma_f32_16x16x32_bf16(pa[mf], vb[nf], acc[mf][nf], 0, 0, 0);
    __syncthreads();
  }

#pragma unroll
  for (int mf = 0; mf < 2; ++mf)
#pragma unroll
    for (int nf = 0; nf < 4; ++nf)
#pragma unroll
      for (int i = 0; i < 4; ++i) {
        const int row = m0 + w * 32 + mf * 16 + g * 4 + i;
        const int dk = nf * 16 + lrow;
        ctx[((size_t)(b * NS + row)) * ND + h * NDK + dk] = (bf16_t)acc[mf][nf][i];
      }
}

// ================================================================ OLD (fallback) path — round-3 proven kernels
template <int ACT>
__global__ __launch_bounds__(256)
void gemm_mfma(const float* __restrict__ A,
               const float* __restrict__ W0, const float* __restrict__ W1,
               const float* __restrict__ W2,
               const float* __restrict__ B0, const float* __restrict__ B1,
               const float* __restrict__ B2,
               float* __restrict__ C, int N, int K, int ldc, int nbm) {
  const int mat = blockIdx.y / nbm;
  const int nb  = blockIdx.y % nbm;
  const float* W    = (mat == 0) ? W0 : (mat == 1) ? W1 : W2;
  const float* bias = (mat == 0) ? B0 : (mat == 1) ? B1 : B2;
  const int m0 = blockIdx.x * 128;
  const int n0 = nb * 128;

  __shared__ bf16_t As[128 * 40];
  __shared__ bf16_t Bs[4 * 128 * 8];

  const int tid  = threadIdx.x;
  const int lane = tid & 63;
  const int wave = tid >> 6;
  const int wm = wave >> 1, wn = wave & 1;
  const int lrow = lane & 15, kc = lane >> 4;
  const int a_kq = tid & 7, a_m = tid >> 3;
  const int b_n = tid & 127, b_h = tid >> 7;

  f32x4 acc[4][4] = {};

  for (int k0 = 0; k0 < K; k0 += 32) {
#pragma unroll
    for (int r = 0; r < 4; ++r) {
      const int m = a_m + r * 32;
      const float4 av = *(const float4*)&A[(size_t)(m0 + m) * K + k0 + a_kq * 4];
      bf16x4 p;
      p[0] = (bf16_t)av.x; p[1] = (bf16_t)av.y;
      p[2] = (bf16_t)av.z; p[3] = (bf16_t)av.w;
      *(bf16x4*)&As[m * 40 + a_kq * 4] = p;
    }
#pragma unroll
    for (int c = 0; c < 2; ++c) {
      const int kcc = b_h * 2 + c;
      bf16x8 p;
#pragma unroll
      for (int j = 0; j < 8; ++j)
        p[j] = (bf16_t)W[(size_t)(k0 + kcc * 8 + j) * N + n0 + b_n];
      *(bf16x8*)&Bs[(kcc * 128 + b_n) * 8] = p;
    }
    __syncthreads();

    bf16x8 af[4], bfv[4];
#pragma unroll
    for (int m = 0; m < 4; ++m)
      af[m] = *(const bf16x8*)&As[(wm * 64 + m * 16 + lrow) * 40 + kc * 8];
#pragma unroll
    for (int n = 0; n < 4; ++n)
      bfv[n] = *(const bf16x8*)&Bs[(kc * 128 + wn * 64 + n * 16 + lrow) * 8];
#pragma unroll
    for (int m = 0; m < 4; ++m)
#pragma unroll
      for (int n = 0; n < 4; ++n)
        acc[m][n] = __builtin_amdgcn_mfma_f32_16x16x32_bf16(af[m], bfv[n], acc[m][n], 0, 0, 0);
    __syncthreads();
  }

  const int crow0 = (lane >> 4) * 4, ccol = lane & 15;
#pragma unroll
  for (int m = 0; m < 4; ++m) {
#pragma unroll
    for (int n = 0; n < 4; ++n) {
      const int ncl = n0 + wn * 64 + n * 16 + ccol;
      const float bv = bias[ncl];
      const size_t ccol_g = (size_t)mat * N + ncl;
#pragma unroll
      for (int i = 0; i < 4; ++i) {
        const int row = m0 + wm * 64 + m * 16 + crow0 + i;
        float v = acc[m][n][i] + bv;
        if (ACT == 1) v = 0.5f * v * (1.0f + erff(v * 0.7071067811865476f));
        C[(size_t)row * ldc + ccol_g] = v;
      }
    }
  }
}

__global__ __launch_bounds__(256)
void attn_scores_kernel(const float* __restrict__ qkv, float* __restrict__ probs) {
  const int q0 = blockIdx.x * QBLK;
  const int h = blockIdx.y, b = blockIdx.z;
  const int NTT = (q0 + QBLK + 127) >> 7;
  const int tid = threadIdx.x;
  const int lane = tid & 63, wq = tid >> 6;
  const int lrow = lane & 15, g = lane >> 4;

  __shared__ bf16_t Qs[QBLK][72];
  __shared__ bf16_t Ks[128][72];
  __shared__ float sMax[4][QBLK];
  __shared__ float sSum[4][QBLK];

  {
    const int r = tid >> 4, c4 = (tid & 15) * 4;
    const float4 qv = *(const float4*)&qkv[((size_t)(b * NS + q0 + r)) * QKVLD + h * NDK + c4];
    bf16x4 p; p[0] = (bf16_t)qv.x; p[1] = (bf16_t)qv.y; p[2] = (bf16_t)qv.z; p[3] = (bf16_t)qv.w;
    *(bf16x4*)&Qs[r][c4] = p;
  }
  __syncthreads();
  const bf16x8 aq0 = *(const bf16x8*)&Qs[lrow][g * 8];
  const bf16x8 aq1 = *(const bf16x8*)&Qs[lrow][32 + g * 8];

  f32x4 sc[16] = {};

#pragma unroll
  for (int tile = 0; tile < 8; ++tile) {
    if (tile < NTT) {
      const int t0 = tile * 128;
#pragma unroll
      for (int p = 0; p < 8; ++p) {
        const int r = (tid >> 4) + p * 16;
        const int c4 = (tid & 15) * 4;
        const float4 kv = *(const float4*)&qkv[((size_t)(b * NS + t0 + r)) * QKVLD + ND + h * NDK + c4];
        bf16x4 pk; pk[0] = (bf16_t)kv.x; pk[1] = (bf16_t)kv.y; pk[2] = (bf16_t)kv.z; pk[3] = (bf16_t)kv.w;
        *(bf16x4*)&Ks[r][c4] = pk;
      }
      __syncthreads();
#pragma unroll
      for (int sub = 0; sub < 2; ++sub) {
        const int tb = wq * 32 + sub * 16;
        const bf16x8 bk0 = *(const bf16x8*)&Ks[tb + lrow][g * 8];
        const bf16x8 bk1 = *(const bf16x8*)&Ks[tb + lrow][32 + g * 8];
        sc[tile * 2 + sub] = __builtin_amdgcn_mfma_f32_16x16x32_bf16(aq0, bk0, sc[tile * 2 + sub], 0, 0, 0);
        sc[tile * 2 + sub] = __builtin_amdgcn_mfma_f32_16x16x32_bf16(aq1, bk1, sc[tile * 2 + sub], 0, 0, 0);
      }
      __syncthreads();
    }
  }

  float mrow[4], srow[4];
#pragma unroll
  for (int i = 0; i < 4; ++i) mrow[i] = -1e30f;
#pragma unroll
  for (int tile = 0; tile < 8; ++tile)
#pragma unroll
    for (int sub = 0; sub < 2; ++sub) {
      const int t = tile * 128 + wq * 32 + sub * 16 + lrow;
#pragma unroll
      for (int i = 0; i < 4; ++i) {
        const int q = q0 + g * 4 + i;
        const float v = (t <= q) ? sc[tile * 2 + sub][i] * 0.125f : -1e30f;
        sc[tile * 2 + sub][i] = v;
        mrow[i] = fmaxf(mrow[i], v);
      }
    }
#pragma unroll
  for (int i = 0; i < 4; ++i) {
    mrow[i] = fmaxf(mrow[i], __shfl_xor(mrow[i], 1));
    mrow[i] = fmaxf(mrow[i], __shfl_xor(mrow[i], 2));
    mrow[i] = fmaxf(mrow[i], __shfl_xor(mrow[i], 4));
    mrow[i] = fmaxf(mrow[i], __shfl_xor(mrow[i], 8));
  }
  if (lrow == 0) {
#pragma unroll
    for (int i = 0; i < 4; ++i) sMax[wq][g * 4 + i] = mrow[i];
  }
  __syncthreads();
#pragma unroll
  for (int i = 0; i < 4; ++i) {
    const int r = g * 4 + i;
    mrow[i] = fmaxf(fmaxf(sMax[0][r], sMax[1][r]), fmaxf(sMax[2][r], sMax[3][r]));
    srow[i] = 0.f;
  }
#pragma unroll
  for (int tile = 0; tile < 8; ++tile)
#pragma unroll
    for (int sub = 0; sub < 2; ++sub)
#pragma unroll
      for (int i = 0; i < 4; ++i) {
        const float e = expf(sc[tile * 2 + sub][i] - mrow[i]);
        sc[tile * 2 + sub][i] = e;
        srow[i] += e;
      }
#pragma unroll
  for (int i = 0; i < 4; ++i) {
    srow[i] += __shfl_xor(srow[i], 1);
    srow[i] += __shfl_xor(srow[i], 2);
    srow[i] += __shfl_xor(srow[i], 4);
    srow[i] += __shfl_xor(srow[i], 8);
  }
  if (lrow == 0) {
#pragma unroll
    for (int i = 0; i < 4; ++i) sSum[wq][g * 4 + i] = srow[i];
  }
  __syncthreads();
  float inv[4];
#pragma unroll
  for (int i = 0; i < 4; ++i) {
    const int r = g * 4 + i;
    inv[i] = 1.f / (sSum[0][r] + sSum[1][r] + sSum[2][r] + sSum[3][r]);
  }

  const size_t rowbase = ((size_t)(b * NH + h)) * NS;
#pragma unroll
  for (int tile = 0; tile < 8; ++tile) {
    if (tile < NTT) {
#pragma unroll
      for (int sub = 0; sub < 2; ++sub) {
        const int t = tile * 128 + wq * 32 + sub * 16 + lrow;
#pragma unroll
        for (int i = 0; i < 4; ++i) {
          const int q = q0 + g * 4 + i;
          probs[(rowbase + q) * NS + t] = sc[tile * 2 + sub][i] * inv[i];
        }
      }
    }
  }
  const int z0 = NTT * 128;
  const int zc = (NS - z0) >> 2;
  const float4 zf = {0.f, 0.f, 0.f, 0.f};
  for (int idx = tid; idx < QBLK * zc; idx += 256) {
    const int r = idx / zc, c = (idx - r * zc) * 4;
    *(float4*)&probs[(rowbase + q0 + r) * NS + z0 + c] = zf;
  }
}

__global__ __launch_bounds__(256)
void attn_pv_kernel(const float* __restrict__ probs, const float* __restrict__ qkv,
                    float* __restrict__ ctx) {
  const int m0 = blockIdx.x * 128;
  const int h = blockIdx.y, b = blockIdx.z;
  const int tid = threadIdx.x;
  const int lane = tid & 63, w = tid >> 6;
  const int lrow = lane & 15, g = lane >> 4;

  __shared__ bf16_t Ps[128][36];
  __shared__ bf16_t Vs[64][40];

  const int nk = (m0 + 128) >> 5;
  f32x4 acc[2][4] = {};
  const size_t pbase = ((size_t)(b * NH + h)) * NS;

  for (int ks = 0; ks < nk; ++ks) {
    const int t0 = ks * 32;
#pragma unroll
    for (int p = 0; p < 4; ++p) {
      const int r = (tid >> 3) + p * 32;
      const int c = (tid & 7) * 4;
      const float4 pv = *(const float4*)&probs[(pbase + m0 + r) * NS + t0 + c];
      bf16x4 pk; pk[0] = (bf16_t)pv.x; pk[1] = (bf16_t)pv.y; pk[2] = (bf16_t)pv.z; pk[3] = (bf16_t)pv.w;
      *(bf16x4*)&Ps[r][c] = pk;
    }
#pragma unroll
    for (int p = 0; p < 2; ++p) {
      const int tt = (tid >> 4) + p * 16;
      const int dk = (tid & 15) * 4;
      const float4 vv = *(const float4*)&qkv[((size_t)(b * NS + t0 + tt)) * QKVLD + 2 * ND + h * NDK + dk];
      Vs[dk + 0][tt] = (bf16_t)vv.x;
      Vs[dk + 1][tt] = (bf16_t)vv.y;
      Vs[dk + 2][tt] = (bf16_t)vv.z;
      Vs[dk + 3][tt] = (bf16_t)vv.w;
    }
    __syncthreads();
    bf16x8 pa[2], vb[4];
#pragma unroll
    for (int mf = 0; mf < 2; ++mf)
      pa[mf] = *(const bf16x8*)&Ps[w * 32 + mf * 16 + lrow][g * 8];
#pragma unroll
    for (int nf = 0; nf < 4; ++nf)
      vb[nf] = *(const bf16x8*)&Vs[nf * 16 + lrow][g * 8];
#pragma unroll
    for (int mf = 0; mf < 2; ++mf)
#pragma unroll
      for (int nf = 0; nf < 4; ++nf)
        acc[mf][nf] = __builtin_amdgcn_mfma_f32_16x16x32_bf16(pa[mf], vb[nf], acc[mf][nf], 0, 0, 0);
    __syncthreads();
  }

#pragma unroll
  for (int mf = 0; mf < 2; ++mf)
#pragma unroll
    for (int nf = 0; nf < 4; ++nf)
#pragma unroll
      for (int i = 0; i < 4; ++i) {
        const int row = m0 + w * 32 + mf * 16 + g * 4 + i;
        const int dk = nf * 16 + lrow;
        ctx[((size_t)(b * NS + row)) * ND + h * NDK + dk] = acc[mf][nf][i];
      }
}

// ---------------------------------------------------------------- launch
extern "C" void kernel_launch(void* const* d_in, const int* in_sizes, int n_in,
                              void* d_out, int out_size, void* d_ws, size_t ws_size,
                              hipStream_t stream) {
  const int*   tokens  = (const int*)d_in[0];
  const float* tok_emb = (const float*)d_in[1];
  const float* Wq = (const float*)d_in[2];
  const float* bq = (const float*)d_in[3];
  const float* Wk = (const float*)d_in[4];
  const float* bk = (const float*)d_in[5];
  const float* Wv = (const float*)d_in[6];
  const float* bv = (const float*)d_in[7];
  const float* Wo = (const float*)d_in[8];
  const float* bo = (const float*)d_in[9];
  const float* ln1_g = (const float*)d_in[10];
  const float* ln1_b = (const float*)d_in[11];
  const float* W1 = (const float*)d_in[12];
  const float* b1 = (const float*)d_in[13];
  const float* W2 = (const float*)d_in[14];
  const float* b2 = (const float*)d_in[15];
  const float* ln2_g = (const float*)d_in[16];
  const float* ln2_b = (const float*)d_in[17];
  const float* lnf_g = (const float*)d_in[18];
  const float* lnf_b = (const float*)d_in[19];
  const float* Wout = (const float*)d_in[20];
  const float* bout = (const float*)d_in[21];

  float* logits   = (float*)d_out;                               // [B,S,V]
  float* attn_all = (float*)d_out + (size_t)NB * NS * NV;        // [L,B,H,S,S]

  const int M = MROWS;
  const dim3 gAttnS(NS / QBLK, NH, NB);
  const dim3 gAttnP(NS / 128, NH, NB);

  // ---------------- fast path: bf16 weights pre-transposed in ws ----------------
  const size_t NEED =
      (size_t)(4 + 4 + 2 + 6 + 2 + 8) * (1 << 20) +      // activations
      (size_t)(6 * QKVLD * ND + 6 * ND * ND + 6 * NDFF * ND + 6 * ND * NDFF + (size_t)NV * ND) * 2;
  if (ws_size >= NEED) {
    char* w = (char*)d_ws;
    float* x    = (float*)w;  w += (size_t)4 << 20;
    float* tmp  = (float*)w;  w += (size_t)4 << 20;
    bf16_t* xb  = (bf16_t*)w; w += (size_t)2 << 20;
    bf16_t* qkv = (bf16_t*)w; w += (size_t)6 << 20;
    bf16_t* ctx = (bf16_t*)w; w += (size_t)2 << 20;
    bf16_t* hh  = (bf16_t*)w; w += (size_t)8 << 20;
    bf16_t* WqkvT = (bf16_t*)w; w += (size_t)6 * QKVLD * ND * 2;
    bf16_t* WoT   = (bf16_t*)w; w += (size_t)6 * ND * ND * 2;
    bf16_t* W1T   = (bf16_t*)w; w += (size_t)6 * NDFF * ND * 2;
    bf16_t* W2T   = (bf16_t*)w; w += (size_t)6 * ND * NDFF * 2;
    bf16_t* WoutT = (bf16_t*)w;

    // weight transposes (f32 [K][N] -> bf16 [N][K])
    transpose_bf16_kernel<<<dim3(8, 8, 6), 256, 0, stream>>>(Wq, WqkvT + 0 * ND * ND % 1 + 0, ND, ND, (size_t)ND * ND, (size_t)QKVLD * ND);
    transpose_bf16_kernel<<<dim3(8, 8, 6), 256, 0, stream>>>(Wk, WqkvT + (size_t)ND * ND, ND, ND, (size_t)ND * ND, (size_t)QKVLD * ND);
    transpose_bf16_kernel<<<dim3(8, 8, 6), 256, 0, stream>>>(Wv, WqkvT + (size_t)2 * ND * ND, ND, ND, (size_t)ND * ND, (size_t)QKVLD * ND);
    transpose_bf16_kernel<<<dim3(8, 8, 6), 256, 0, stream>>>(Wo, WoT, ND, ND, (size_t)ND * ND, (size_t)ND * ND);
    transpose_bf16_kernel<<<dim3(32, 8, 6), 256, 0, stream>>>(W1, W1T, ND, NDFF, (size_t)ND * NDFF, (size_t)NDFF * ND);
    transpose_bf16_kernel<<<dim3(8, 32, 6), 256, 0, stream>>>(W2, W2T, NDFF, ND, (size_t)NDFF * ND, (size_t)ND * NDFF);
    transpose_bf16_kernel<<<dim3(500, 8, 1), 256, 0, stream>>>(Wout, WoutT, ND, NV, 0, 0);

    embed_kernel<<<M, 256, 0, stream>>>(tokens, tok_emb, x, xb);

    const dim3 gQKV(M / 128, QKVLD / 128);   // (16, 12)
    const dim3 gProj(M / 128, ND / 128);     // (16, 4)
    const dim3 gFF1(M / 128, NDFF / 128);    // (16, 16)
    const dim3 gOut(M / 128, NV / 128);      // (16, 250)

    for (int l = 0; l < NL; ++l) {
      gemm_bt<0, 1><<<gQKV, 256, 0, stream>>>(xb, WqkvT + (size_t)l * QKVLD * ND,
          bq + l * ND, bk + l * ND, bv + l * ND, qkv, QKVLD, ND, ND, QKVLD, 9, 511);

      float* probs_l = attn_all + (size_t)l * NB * NH * NS * NS;
      attn_scores_b<<<gAttnS, 256, 0, stream>>>(qkv, probs_l);
      attn_pv_b<<<gAttnP, 256, 0, stream>>>(probs_l, qkv, ctx);

      gemm_bt<0, 0><<<gProj, 256, 0, stream>>>(ctx, WoT + (size_t)l * ND * ND,
          bo + l * ND, bo, bo, tmp, ND, ND, ND, ND, 30, 0x3fffffff);
      add_ln_kernel<<<M, 256, 0, stream>>>(x, tmp, ln1_g + l * ND, ln1_b + l * ND, xb);

      gemm_bt<1, 1><<<gFF1, 256, 0, stream>>>(xb, W1T + (size_t)l * NDFF * ND,
          b1 + l * NDFF, b1, b1, hh, NDFF, ND, ND, NDFF, 30, 0x3fffffff);
      gemm_bt<0, 0><<<gProj, 256, 0, stream>>>(hh, W2T + (size_t)l * ND * NDFF,
          b2 + l * ND, b2, b2, tmp, ND, NDFF, NDFF, ND, 30, 0x3fffffff);
      add_ln_kernel<<<M, 256, 0, stream>>>(x, tmp, ln2_g + l * ND, ln2_b + l * ND, xb);
    }

    add_ln_kernel<<<M, 256, 0, stream>>>(x, nullptr, lnf_g, lnf_b, xb);
    gemm_bt<0, 0><<<gOut, 256, 0, stream>>>(xb, WoutT, bout, bout, bout,
        logits, NV, ND, ND, NV, 30, 0x3fffffff);
    return;
  }

  // ---------------- fallback: round-3 path ----------------
  float* ws = (float*)d_ws;
  const size_t U = (size_t)MROWS * ND;
  float* x   = ws;
  float* qkv = ws + U;
  float* ctx = ws + 4 * U;
  float* tmp = ws + 5 * U;
  float* h   = ws + U;

  embed_kernel<<<M, 256, 0, stream>>>(tokens, tok_emb, x, nullptr);

  const dim3 gQKV(M / 128, 12);
  const dim3 gProj(M / 128, 4);
  const dim3 gFF1(M / 128, 16);
  const dim3 gOut(M / 128, NV / 128);

  for (int l = 0; l < NL; ++l) {
    const float* Wq_l = Wq + (size_t)l * ND * ND;
    const float* Wk_l = Wk + (size_t)l * ND * ND;
    const float* Wv_l = Wv + (size_t)l * ND * ND;
    const float* Wo_l = Wo + (size_t)l * ND * ND;
    const float* W1_l = W1 + (size_t)l * ND * NDFF;
    const float* W2_l = W2 + (size_t)l * NDFF * ND;

    gemm_mfma<0><<<gQKV, 256, 0, stream>>>(x, Wq_l, Wk_l, Wv_l,
                                           bq + l * ND, bk + l * ND, bv + l * ND,
                                           qkv, ND, ND, QKVLD, 4);

    float* probs_l = attn_all + (size_t)l * NB * NH * NS * NS;
    attn_scores_kernel<<<gAttnS, 256, 0, stream>>>(qkv, probs_l);
    attn_pv_kernel<<<gAttnP, 256, 0, stream>>>(probs_l, qkv, ctx);

    gemm_mfma<0><<<gProj, 256, 0, stream>>>(ctx, Wo_l, Wo_l, Wo_l,
                                            bo + l * ND, bo + l * ND, bo + l * ND,
                                            tmp, ND, ND, ND, 4);
    add_ln_kernel<<<M, 256, 0, stream>>>(x, tmp, ln1_g + l * ND, ln1_b + l * ND, nullptr);

    gemm_mfma<1><<<gFF1, 256, 0, stream>>>(x, W1_l, W1_l, W1_l,
                                           b1 + l * NDFF, b1 + l * NDFF, b1 + l * NDFF,
                                           h, NDFF, ND, NDFF, 16);
    gemm_mfma<0><<<gProj, 256, 0, stream>>>(h, W2_l, W2_l, W2_l,
                                            b2 + l * ND, b2 + l * ND, b2 + l * ND,
                                            tmp, ND, NDFF, ND, 4);
    add_ln_kernel<<<M, 256, 0, stream>>>(x, tmp, ln2_g + l * ND, ln2_b + l * ND, nullptr);
  }

  add_ln_kernel<<<M, 256, 0, stream>>>(x, nullptr, lnf_g, lnf_b, nullptr);

  gemm_mfma<0><<<gOut, 256, 0, stream>>>(x, Wout, Wout, Wout, bout, bout, bout,
                                         logits, NV, ND, NV, 250);
}

// Round 5
// 1086.082 us; speedup vs baseline: 6.0644x; 1.0837x over previous
//
#include <hip/hip_runtime.h>
#include <math.h>

#define NB 2
#define NS 1024
#define NH 8
#define NDK 64
#define ND 512
#define NDFF 2048
#define NV 32000
#define NL 6
#define MROWS (NB * NS)
#define QKVLD (3 * ND)   // 1536

using bf16_t = __bf16;
using bf16x4 = __attribute__((ext_vector_type(4))) __bf16;
using bf16x8 = __attribute__((ext_vector_type(8))) __bf16;
using f32x4  = __attribute__((ext_vector_type(4))) float;

__device__ __forceinline__ void gload_lds16(const bf16_t* g, bf16_t* l) {
  __builtin_amdgcn_global_load_lds(
      (const __attribute__((address_space(1))) void*)g,
      (__attribute__((address_space(3))) void*)l, 16, 0, 0);
}

__device__ __forceinline__ float gelu_exact(float v) {
  return 0.5f * v * (1.0f + erff(v * 0.7071067811865476f));
}

// ---------------------------------------------------------------- embed
__global__ void embed_kernel(const int* __restrict__ tokens,
                             const float* __restrict__ emb,
                             float* __restrict__ x, bf16_t* __restrict__ xb) {
  const int row = blockIdx.x;            // b*NS + s
  const int s = row & (NS - 1);
  const int tok = tokens[row];
  const int tid = threadIdx.x;
  const float SQRTD = 22.627416997969522f;             // sqrt(512)
  const float C = -9.210340371976184f / (float)ND;     // -ln(10000)/D
#pragma unroll
  for (int i = 0; i < 2; ++i) {
    const int d = tid + i * 256;
    const int pair = d >> 1;
    const float div = expf((float)(2 * pair) * C);
    const float ang = (float)s * div;
    const float pe = (d & 1) ? cosf(ang) : sinf(ang);
    const float v = emb[(size_t)tok * ND + d] * SQRTD + pe;
    x[(size_t)row * ND + d] = v;
    xb[(size_t)row * ND + d] = (bf16_t)v;
  }
}

// ---------------------------------------------------------------- residual add + LayerNorm
__global__ __launch_bounds__(256)
void add_ln_kernel(float* __restrict__ x, const float* __restrict__ y,
                   const float* __restrict__ g, const float* __restrict__ bb,
                   bf16_t* __restrict__ xb) {
  const int row = blockIdx.x, tid = threadIdx.x;
  const size_t base = (size_t)row * ND;
  float v0 = x[base + tid], v1 = x[base + tid + 256];
  if (y) { v0 += y[base + tid]; v1 += y[base + tid + 256]; }
  __shared__ float red[256];
  red[tid] = v0 + v1; __syncthreads();
  for (int o = 128; o > 0; o >>= 1) {
    if (tid < o) red[tid] += red[tid + o];
    __syncthreads();
  }
  const float mean = red[0] * (1.f / (float)ND);
  __syncthreads();
  const float d0 = v0 - mean, d1 = v1 - mean;
  red[tid] = d0 * d0 + d1 * d1; __syncthreads();
  for (int o = 128; o > 0; o >>= 1) {
    if (tid < o) red[tid] += red[tid + o];
    __syncthreads();
  }
  const float inv = 1.f / sqrtf(red[0] * (1.f / (float)ND) + 1e-5f);
  const float o0 = d0 * inv * g[tid]       + bb[tid];
  const float o1 = d1 * inv * g[tid + 256] + bb[tid + 256];
  x[base + tid] = o0;
  x[base + tid + 256] = o1;
  xb[base + tid] = (bf16_t)o0; xb[base + tid + 256] = (bf16_t)o1;
}

// ---------------------------------------------------------------- transpose+convert f32 [K][N] -> bf16 [N][K]
__global__ __launch_bounds__(256)
void transpose_bf16_kernel(const float* __restrict__ src, bf16_t* __restrict__ dst,
                           int K, int N, size_t sstride, size_t dstride) {
  __shared__ bf16_t T[64][72];
  const float* s = src + (size_t)blockIdx.z * sstride;
  bf16_t* d = dst + (size_t)blockIdx.z * dstride;
  const int n0 = blockIdx.x * 64, k0 = blockIdx.y * 64;
  const int tid = threadIdx.x;
#pragma unroll
  for (int it = 0; it < 4; ++it) {
    const int k = (tid >> 4) + it * 16;
    const int c = (tid & 15) * 4;
    const float4 v = *(const float4*)&s[(size_t)(k0 + k) * N + n0 + c];
    T[c + 0][k] = (bf16_t)v.x;
    T[c + 1][k] = (bf16_t)v.y;
    T[c + 2][k] = (bf16_t)v.z;
    T[c + 3][k] = (bf16_t)v.w;
  }
  __syncthreads();
  const int n = tid >> 2, kk = (tid & 3) * 16;
  bf16x8 a = *(const bf16x8*)&T[n][kk];
  bf16x8 b = *(const bf16x8*)&T[n][kk + 8];
  *(bf16x8*)&d[(size_t)(n0 + n) * K + k0 + kk] = a;
  *(bf16x8*)&d[(size_t)(n0 + n) * K + k0 + kk + 8] = b;
}

// combined Wq/Wk/Wv/Wo transpose: grid (8, 8, 24); z -> mat (z/6), layer (z%6)
__global__ __launch_bounds__(256)
void transpose_qkvo_kernel(const float* __restrict__ Wq, const float* __restrict__ Wk,
                           const float* __restrict__ Wv, const float* __restrict__ Wo,
                           bf16_t* __restrict__ WqkvT, bf16_t* __restrict__ WoT) {
  __shared__ bf16_t T[64][72];
  const int z = blockIdx.z;
  const int mat = z / 6, layer = z % 6;
  const float* s = ((mat == 0) ? Wq : (mat == 1) ? Wk : (mat == 2) ? Wv : Wo)
                   + (size_t)layer * ND * ND;
  bf16_t* d = (mat < 3) ? (WqkvT + (size_t)layer * QKVLD * ND + (size_t)mat * ND * ND)
                        : (WoT + (size_t)layer * ND * ND);
  const int n0 = blockIdx.x * 64, k0 = blockIdx.y * 64;
  const int tid = threadIdx.x;
#pragma unroll
  for (int it = 0; it < 4; ++it) {
    const int k = (tid >> 4) + it * 16;
    const int c = (tid & 15) * 4;
    const float4 v = *(const float4*)&s[(size_t)(k0 + k) * ND + n0 + c];
    T[c + 0][k] = (bf16_t)v.x;
    T[c + 1][k] = (bf16_t)v.y;
    T[c + 2][k] = (bf16_t)v.z;
    T[c + 3][k] = (bf16_t)v.w;
  }
  __syncthreads();
  const int n = tid >> 2, kk = (tid & 3) * 16;
  bf16x8 a = *(const bf16x8*)&T[n][kk];
  bf16x8 b = *(const bf16x8*)&T[n][kk + 8];
  *(bf16x8*)&d[(size_t)(n0 + n) * ND + k0 + kk] = a;
  *(bf16x8*)&d[(size_t)(n0 + n) * ND + k0 + kk + 8] = b;
}

// ---------------------------------------------------------------- 128x128 GEMM: A bf16 [M][lda], Wt bf16 [N][K]
// swapped-operand MFMA -> lane owns 4 consecutive output cols (float4 stores)
template <int ACT, int OUTBF>
__global__ __launch_bounds__(256)
void gemm_bt(const bf16_t* __restrict__ A, const bf16_t* __restrict__ Wt,
             const float* __restrict__ B0, const float* __restrict__ B1,
             const float* __restrict__ B2,
             void* __restrict__ Cout, int N, int K, int lda, int ldc,
             int bshift, int bmask) {
  __shared__ bf16_t As[128 * 32];
  __shared__ bf16_t Bs[128 * 32];
  const int tid = threadIdx.x, lane = tid & 63, w = tid >> 6;
  const int wm = w >> 1, wn = w & 1;
  const int lcol = lane & 15, hi = lane >> 4;
  const int m0 = blockIdx.x * 128, n0 = blockIdx.y * 128;
  const int srow_l = lane >> 2;
  const int sslot = lane & 3;

  f32x4 acc[4][4] = {};

  for (int k0 = 0; k0 < K; k0 += 32) {
#pragma unroll
    for (int t = 0; t < 2; ++t) {
      const int row = t * 64 + w * 16 + srow_l;
      const int gs = sslot ^ ((row >> 1) & 3);
      gload_lds16(&A[(size_t)(m0 + row) * lda + k0 + gs * 8], &As[(t * 64 + w * 16) * 32]);
      gload_lds16(&Wt[(size_t)(n0 + row) * K + k0 + gs * 8], &Bs[(t * 64 + w * 16) * 32]);
    }
    __syncthreads();

    bf16x8 af[4], bf[4];
#pragma unroll
    for (int m = 0; m < 4; ++m) {
      const int r = wm * 64 + m * 16 + lcol;
      af[m] = *(const bf16x8*)&As[r * 32 + ((hi ^ ((r >> 1) & 3)) * 8)];
    }
#pragma unroll
    for (int n = 0; n < 4; ++n) {
      const int r = wn * 64 + n * 16 + lcol;
      bf[n] = *(const bf16x8*)&Bs[r * 32 + ((hi ^ ((r >> 1) & 3)) * 8)];
    }
#pragma unroll
    for (int m = 0; m < 4; ++m)
#pragma unroll
      for (int n = 0; n < 4; ++n)
        acc[m][n] = __builtin_amdgcn_mfma_f32_16x16x32_bf16(bf[n], af[m], acc[m][n], 0, 0, 0);
    __syncthreads();
  }

  // C-layout after swap: row = m-index via lcol, col = n-index via hi*4+i
#pragma unroll
  for (int m = 0; m < 4; ++m) {
    const int row = m0 + wm * 64 + m * 16 + lcol;
#pragma unroll
    for (int n = 0; n < 4; ++n) {
      const int col = n0 + wn * 64 + n * 16 + hi * 4;
      const int sel = col >> bshift;
      const float* Bp = (sel == 0) ? B0 : (sel == 1) ? B1 : B2;
      const f32x4 bv = *(const f32x4*)&Bp[col & bmask];
      f32x4 v;
#pragma unroll
      for (int i = 0; i < 4; ++i) {
        float t = acc[m][n][i] + bv[i];
        if (ACT == 1) t = gelu_exact(t);
        v[i] = t;
      }
      if (OUTBF) {
        bf16x4 o;
#pragma unroll
        for (int i = 0; i < 4; ++i) o[i] = (bf16_t)v[i];
        *(bf16x4*)&((bf16_t*)Cout)[(size_t)row * ldc + col] = o;
      } else {
        *(f32x4*)&((float*)Cout)[(size_t)row * ldc + col] = v;
      }
    }
  }
}

// ---------------------------------------------------------------- 64x64 GEMM (full-chip util for N=512 mats)
template <int ACT, int OUTBF>
__global__ __launch_bounds__(256)
void gemm_bt64(const bf16_t* __restrict__ A, const bf16_t* __restrict__ Wt,
               const float* __restrict__ bias,
               void* __restrict__ Cout, int N, int K, int lda, int ldc) {
  __shared__ bf16_t As[64 * 32];
  __shared__ bf16_t Bs[64 * 32];
  const int tid = threadIdx.x, lane = tid & 63, w = tid >> 6;
  const int wm = w >> 1, wn = w & 1;
  const int lcol = lane & 15, hi = lane >> 4;
  const int m0 = blockIdx.x * 64, n0 = blockIdx.y * 64;
  const int srow_l = lane >> 2;
  const int sslot = lane & 3;

  f32x4 acc[2][2] = {};

  for (int k0 = 0; k0 < K; k0 += 32) {
    const int row = w * 16 + srow_l;
    const int gs = sslot ^ ((row >> 1) & 3);
    gload_lds16(&A[(size_t)(m0 + row) * lda + k0 + gs * 8], &As[(w * 16) * 32]);
    gload_lds16(&Wt[(size_t)(n0 + row) * K + k0 + gs * 8], &Bs[(w * 16) * 32]);
    __syncthreads();

    bf16x8 af[2], bf[2];
#pragma unroll
    for (int m = 0; m < 2; ++m) {
      const int r = wm * 32 + m * 16 + lcol;
      af[m] = *(const bf16x8*)&As[r * 32 + ((hi ^ ((r >> 1) & 3)) * 8)];
    }
#pragma unroll
    for (int n = 0; n < 2; ++n) {
      const int r = wn * 32 + n * 16 + lcol;
      bf[n] = *(const bf16x8*)&Bs[r * 32 + ((hi ^ ((r >> 1) & 3)) * 8)];
    }
#pragma unroll
    for (int m = 0; m < 2; ++m)
#pragma unroll
      for (int n = 0; n < 2; ++n)
        acc[m][n] = __builtin_amdgcn_mfma_f32_16x16x32_bf16(bf[n], af[m], acc[m][n], 0, 0, 0);
    __syncthreads();
  }

#pragma unroll
  for (int m = 0; m < 2; ++m) {
    const int row = m0 + wm * 32 + m * 16 + lcol;
#pragma unroll
    for (int n = 0; n < 2; ++n) {
      const int col = n0 + wn * 32 + n * 16 + hi * 4;
      const f32x4 bv = *(const f32x4*)&bias[col];
      f32x4 v;
#pragma unroll
      for (int i = 0; i < 4; ++i) {
        float t = acc[m][n][i] + bv[i];
        if (ACT == 1) t = gelu_exact(t);
        v[i] = t;
      }
      if (OUTBF) {
        bf16x4 o;
#pragma unroll
        for (int i = 0; i < 4; ++i) o[i] = (bf16_t)v[i];
        *(bf16x4*)&((bf16_t*)Cout)[(size_t)row * ldc + col] = o;
      } else {
        *(f32x4*)&((float*)Cout)[(size_t)row * ldc + col] = v;
      }
    }
  }
}

// ---------------------------------------------------------------- fused attention
// grid (16, NH, NB); block 256 (4 waves). Per block: 64 q-rows for one (b,h).
// Pass A: online (m,s) over causal 128-t tiles. Pass B: recompute scores,
// write normalized probs (f32, float4) + P bf16 to LDS, accumulate PV.
__global__ __launch_bounds__(256)
void attn_fused(const bf16_t* __restrict__ qkv, float* __restrict__ probs,
                bf16_t* __restrict__ ctx) {
  const int qt = 15 - blockIdx.x;            // heavy blocks first
  const int h = blockIdx.y, b = blockIdx.z;
  const int q0 = qt * 64;
  const int NTT = (q0 >> 7) + 1;
  const int tid = threadIdx.x, lane = tid & 63, wq = tid >> 6;
  const int lcol = lane & 15, hi = lane >> 4;

  __shared__ bf16_t Qs[64][72];
  __shared__ bf16_t Ks[128][72];
  __shared__ bf16_t Vs[64][132];
  __shared__ bf16_t Ps[64][132];

  // stage Q 64x64
  {
    const int r = tid >> 2, c = (tid & 3) * 16;
    const bf16_t* src = &qkv[((size_t)(b * NS + q0 + r)) * QKVLD + h * NDK + c];
    *(bf16x8*)&Qs[r][c]     = *(const bf16x8*)&src[0];
    *(bf16x8*)&Qs[r][c + 8] = *(const bf16x8*)&src[8];
  }
  __syncthreads();
  const bf16x8 qf0 = *(const bf16x8*)&Qs[wq * 16 + lcol][hi * 8];
  const bf16x8 qf1 = *(const bf16x8*)&Qs[wq * 16 + lcol][32 + hi * 8];
  const int qrow = q0 + wq * 16 + lcol;      // the q-row this lane tracks
  const float scale = 0.125f;

  float m_run = -1e30f, s_run = 0.f;

  // ---------------- pass A: online max/sum
  for (int tt = 0; tt < NTT; ++tt) {
    const int t0 = tt * 128;
    {
      const int r = tid >> 1, cb = (tid & 1) * 32;
      const bf16_t* src = &qkv[((size_t)(b * NS + t0 + r)) * QKVLD + ND + h * NDK + cb];
#pragma unroll
      for (int j = 0; j < 4; ++j)
        *(bf16x8*)&Ks[r][cb + j * 8] = *(const bf16x8*)&src[j * 8];
    }
    __syncthreads();

    float tmax = -1e30f;
    f32x4 sc[8];
#pragma unroll
    for (int f = 0; f < 8; ++f) {
      f32x4 s4 = {};
      const bf16x8 ka0 = *(const bf16x8*)&Ks[f * 16 + lcol][hi * 8];
      const bf16x8 ka1 = *(const bf16x8*)&Ks[f * 16 + lcol][32 + hi * 8];
      s4 = __builtin_amdgcn_mfma_f32_16x16x32_bf16(ka0, qf0, s4, 0, 0, 0);
      s4 = __builtin_amdgcn_mfma_f32_16x16x32_bf16(ka1, qf1, s4, 0, 0, 0);
#pragma unroll
      for (int i = 0; i < 4; ++i) {
        const int t = t0 + f * 16 + hi * 4 + i;
        const float v = (t <= qrow) ? s4[i] * scale : -1e30f;
        s4[i] = v;
        tmax = fmaxf(tmax, v);
      }
      sc[f] = s4;
    }
    tmax = fmaxf(tmax, __shfl_xor(tmax, 16));
    tmax = fmaxf(tmax, __shfl_xor(tmax, 32));
    const float m_new = fmaxf(m_run, tmax);
    float sum = 0.f;
#pragma unroll
    for (int f = 0; f < 8; ++f)
#pragma unroll
      for (int i = 0; i < 4; ++i) sum += expf(sc[f][i] - m_new);
    sum += __shfl_xor(sum, 16);
    sum += __shfl_xor(sum, 32);
    s_run = s_run * expf(m_run - m_new) + sum;
    m_run = m_new;
    __syncthreads();
  }
  const float inv = 1.f / s_run;

  // ---------------- pass B: probs + PV
  f32x4 cacc[4] = {};
  const size_t prow = (((size_t)b * NH + h) * NS + qrow) * NS;
  for (int tt = 0; tt < NTT; ++tt) {
    const int t0 = tt * 128;
    {
      const int r = tid >> 1, cb = (tid & 1) * 32;
      const bf16_t* src = &qkv[((size_t)(b * NS + t0 + r)) * QKVLD + ND + h * NDK + cb];
#pragma unroll
      for (int j = 0; j < 4; ++j)
        *(bf16x8*)&Ks[r][cb + j * 8] = *(const bf16x8*)&src[j * 8];
    }
    {
      const int t = tid >> 1, db = (tid & 1) * 32;
      const bf16_t* src = &qkv[((size_t)(b * NS + t0 + t)) * QKVLD + 2 * ND + h * NDK + db];
#pragma unroll
      for (int j = 0; j < 4; ++j) {
        const bf16x8 v8 = *(const bf16x8*)&src[j * 8];
#pragma unroll
        for (int jj = 0; jj < 8; ++jj) Vs[db + j * 8 + jj][t] = v8[jj];
      }
    }
    __syncthreads();

#pragma unroll
    for (int f = 0; f < 8; ++f) {
      f32x4 s4 = {};
      const bf16x8 ka0 = *(const bf16x8*)&Ks[f * 16 + lcol][hi * 8];
      const bf16x8 ka1 = *(const bf16x8*)&Ks[f * 16 + lcol][32 + hi * 8];
      s4 = __builtin_amdgcn_mfma_f32_16x16x32_bf16(ka0, qf0, s4, 0, 0, 0);
      s4 = __builtin_amdgcn_mfma_f32_16x16x32_bf16(ka1, qf1, s4, 0, 0, 0);
      f32x4 pw;
      bf16x4 pb;
#pragma unroll
      for (int i = 0; i < 4; ++i) {
        const int t = t0 + f * 16 + hi * 4 + i;
        const float v = (t <= qrow) ? s4[i] * scale : -1e30f;
        const float p = expf(v - m_run) * inv;
        pw[i] = p;
        pb[i] = (bf16_t)p;
      }
      *(f32x4*)&probs[prow + t0 + f * 16 + hi * 4] = pw;
      *(bf16x4*)&Ps[wq * 16 + lcol][f * 16 + hi * 4] = pb;
    }

    // PV: K-dim = 128 t
#pragma unroll
    for (int ks = 0; ks < 4; ++ks) {
      const bf16x8 pf = *(const bf16x8*)&Ps[wq * 16 + lcol][ks * 32 + hi * 8];
#pragma unroll
      for (int df = 0; df < 4; ++df) {
        const bf16x8 vf = *(const bf16x8*)&Vs[df * 16 + lcol][ks * 32 + hi * 8];
        cacc[df] = __builtin_amdgcn_mfma_f32_16x16x32_bf16(vf, pf, cacc[df], 0, 0, 0);
      }
    }
    __syncthreads();
  }

  // ctx write: lane's q = lcol-based row, 4 consecutive dk
#pragma unroll
  for (int df = 0; df < 4; ++df) {
    bf16x4 o;
#pragma unroll
    for (int i = 0; i < 4; ++i) o[i] = (bf16_t)cacc[df][i];
    *(bf16x4*)&ctx[((size_t)(b * NS + q0 + wq * 16 + lcol)) * ND + h * NDK + df * 16 + hi * 4] = o;
  }

  // zero-fill t in [NTT*128, NS)
  const int z0 = NTT * 128;
  const int nz = (NS - z0) >> 2;
  if (nz > 0) {
    const f32x4 zf = {0.f, 0.f, 0.f, 0.f};
    for (int idx = tid; idx < 64 * nz; idx += 256) {
      const int r = idx / nz, c = (idx - r * nz) * 4;
      *(f32x4*)&probs[(((size_t)b * NH + h) * NS + q0 + r) * NS + z0 + c] = zf;
    }
  }
}

// ---------------------------------------------------------------- launch
extern "C" void kernel_launch(void* const* d_in, const int* in_sizes, int n_in,
                              void* d_out, int out_size, void* d_ws, size_t ws_size,
                              hipStream_t stream) {
  const int*   tokens  = (const int*)d_in[0];
  const float* tok_emb = (const float*)d_in[1];
  const float* Wq = (const float*)d_in[2];
  const float* bq = (const float*)d_in[3];
  const float* Wk = (const float*)d_in[4];
  const float* bk = (const float*)d_in[5];
  const float* Wv = (const float*)d_in[6];
  const float* bv = (const float*)d_in[7];
  const float* Wo = (const float*)d_in[8];
  const float* bo = (const float*)d_in[9];
  const float* ln1_g = (const float*)d_in[10];
  const float* ln1_b = (const float*)d_in[11];
  const float* W1 = (const float*)d_in[12];
  const float* b1 = (const float*)d_in[13];
  const float* W2 = (const float*)d_in[14];
  const float* b2 = (const float*)d_in[15];
  const float* ln2_g = (const float*)d_in[16];
  const float* ln2_b = (const float*)d_in[17];
  const float* lnf_g = (const float*)d_in[18];
  const float* lnf_b = (const float*)d_in[19];
  const float* Wout = (const float*)d_in[20];
  const float* bout = (const float*)d_in[21];

  float* logits   = (float*)d_out;                               // [B,S,V]
  float* attn_all = (float*)d_out + (size_t)NB * NS * NV;        // [L,B,H,S,S]

  const size_t NEED =
      (size_t)(4 + 4 + 2 + 6 + 2 + 8) * (1 << 20) +
      (size_t)(6 * QKVLD * ND + 6 * ND * ND + 6 * NDFF * ND + 6 * ND * NDFF + (size_t)NV * ND) * 2;
  if (ws_size < NEED) return;   // never expected (r4 verified ws >= NEED)

  char* w = (char*)d_ws;
  float* x    = (float*)w;  w += (size_t)4 << 20;
  float* tmp  = (float*)w;  w += (size_t)4 << 20;
  bf16_t* xb  = (bf16_t*)w; w += (size_t)2 << 20;
  bf16_t* qkv = (bf16_t*)w; w += (size_t)6 << 20;
  bf16_t* ctx = (bf16_t*)w; w += (size_t)2 << 20;
  bf16_t* hh  = (bf16_t*)w; w += (size_t)8 << 20;
  bf16_t* WqkvT = (bf16_t*)w; w += (size_t)6 * QKVLD * ND * 2;
  bf16_t* WoT   = (bf16_t*)w; w += (size_t)6 * ND * ND * 2;
  bf16_t* W1T   = (bf16_t*)w; w += (size_t)6 * NDFF * ND * 2;
  bf16_t* W2T   = (bf16_t*)w; w += (size_t)6 * ND * NDFF * 2;
  bf16_t* WoutT = (bf16_t*)w;

  const int M = MROWS;

  transpose_qkvo_kernel<<<dim3(8, 8, 24), 256, 0, stream>>>(Wq, Wk, Wv, Wo, WqkvT, WoT);
  transpose_bf16_kernel<<<dim3(32, 8, 6), 256, 0, stream>>>(W1, W1T, ND, NDFF, (size_t)ND * NDFF, (size_t)NDFF * ND);
  transpose_bf16_kernel<<<dim3(8, 32, 6), 256, 0, stream>>>(W2, W2T, NDFF, ND, (size_t)NDFF * ND, (size_t)ND * NDFF);
  transpose_bf16_kernel<<<dim3(500, 8, 1), 256, 0, stream>>>(Wout, WoutT, ND, NV, 0, 0);

  embed_kernel<<<M, 256, 0, stream>>>(tokens, tok_emb, x, xb);

  const dim3 gQKV(M / 128, QKVLD / 128);   // (16, 12)
  const dim3 gFF1(M / 128, NDFF / 128);    // (16, 16)
  const dim3 gOut(M / 128, NV / 128);      // (16, 250)
  const dim3 g64(M / 64, ND / 64);         // (32, 8) full-chip
  const dim3 gAttn(16, NH, NB);            // (16, 8, 2)

  for (int l = 0; l < NL; ++l) {
    gemm_bt<0, 1><<<gQKV, 256, 0, stream>>>(xb, WqkvT + (size_t)l * QKVLD * ND,
        bq + l * ND, bk + l * ND, bv + l * ND, qkv, QKVLD, ND, ND, QKVLD, 9, 511);

    float* probs_l = attn_all + (size_t)l * NB * NH * NS * NS;
    attn_fused<<<gAttn, 256, 0, stream>>>(qkv, probs_l, ctx);

    gemm_bt64<0, 0><<<g64, 256, 0, stream>>>(ctx, WoT + (size_t)l * ND * ND,
        bo + l * ND, tmp, ND, ND, ND, ND);
    add_ln_kernel<<<M, 256, 0, stream>>>(x, tmp, ln1_g + l * ND, ln1_b + l * ND, xb);

    gemm_bt<1, 1><<<gFF1, 256, 0, stream>>>(xb, W1T + (size_t)l * NDFF * ND,
        b1 + l * NDFF, b1, b1, hh, NDFF, ND, ND, NDFF, 30, 0x3fffffff);
    gemm_bt64<0, 0><<<g64, 256, 0, stream>>>(hh, W2T + (size_t)l * ND * NDFF,
        b2 + l * ND, tmp, ND, NDFF, NDFF, ND);
    add_ln_kernel<<<M, 256, 0, stream>>>(x, tmp, ln2_g + l * ND, ln2_b + l * ND, xb);
  }

  add_ln_kernel<<<M, 256, 0, stream>>>(x, nullptr, lnf_g, lnf_b, xb);

  gemm_bt<0, 0><<<gOut, 256, 0, stream>>>(xb, WoutT, bout, bout, bout,
      logits, NV, ND, ND, NV, 30, 0x3fffffff);
}